// Round 7
// baseline (1674.415 us; speedup 1.0000x reference)
//
#include <hip/hip_runtime.h>

#define NU_ 100000
#define NI_ 50000
#define NA_ 5000
#define FEAT_ 256
#define H_ 128
#define ER_ 1000000
#define ES_ 500000
#define EH_ 250000

#define NTOT_ (3 * NI_ + NU_ + NA_)      // 255000 combined counters
#define ETOT_ (ER_ + ES_ + EH_)          // 1,750,000 edges
#define NB_ ((NTOT_ + 255) / 256)        // 997 coarse buckets (256 nodes each)
#define GB_ (NB_ * 8)                    // 7976 (bucket, xcd-group) regions
// counter-array bases (order defines pool layout via global scan)
#define B_RI 0
#define B_RU (NI_)
#define B_SI (NI_ + NU_)
#define B_HA (2 * NI_ + NU_)
#define B_HI (2 * NI_ + NU_ + NA_)

typedef long long i64;
typedef unsigned short u16;
typedef unsigned int u32;
typedef __attribute__((ext_vector_type(8))) short bf16x8;
typedef __attribute__((ext_vector_type(4))) float f32x4;

__device__ __forceinline__ u16 f2bf(float v) {           // round-to-nearest-even
    u32 b = __float_as_uint(v);
    b += 0x7fff + ((b >> 16) & 1);
    return (u16)(b >> 16);
}
__device__ __forceinline__ float bf2f(u16 v) {
    return __uint_as_float((u32)v << 16);
}

__global__ __launch_bounds__(256) void fillz_kernel(float4* __restrict__ p, long n4) {
    long i = (long)blockIdx.x * 256 + threadIdx.x;
    if (i < n4) p[i] = make_float4(0.f, 0.f, 0.f, 0.f);
}

// fp32 -> bf16 table convert
__global__ __launch_bounds__(256) void tobf_kernel(const float4* __restrict__ in,
                                                   ushort4* __restrict__ out, long n4) {
    long i = (long)blockIdx.x * 256 + threadIdx.x;
    if (i >= n4) return;
    float4 v = in[i];
    ushort4 o;
    o.x = f2bf(v.x); o.y = f2bf(v.y); o.z = f2bf(v.z); o.w = f2bf(v.w);
    out[i] = o;
}

// ---- fused degree + region counts over all 5 graphs ----
// g = blockIdx&7 tracks the (approx) XCD of the block that will scatter this
// edge in fillA (identical grid mapping there), giving per-XCD regions.
__global__ __launch_bounds__(256) void countall_kernel(const int* __restrict__ er,
                                                       const int* __restrict__ es,
                                                       const int* __restrict__ eh,
                                                       int* __restrict__ cnt,
                                                       int* __restrict__ gbc) {
    int g = blockIdx.x & 7;
    int gid = blockIdx.x * 256 + threadIdx.x;
    if (gid < ER_) {
        int c0 = B_RI + er[ER_ + gid];
        int c1 = B_RU + er[gid];
        atomicAdd(&cnt[c0], 1); atomicAdd(&gbc[(c0 >> 8) * 8 + g], 1);
        atomicAdd(&cnt[c1], 1); atomicAdd(&gbc[(c1 >> 8) * 8 + g], 1);
    } else if (gid < ER_ + ES_) {
        int e = gid - ER_;
        int c0 = B_SI + es[ES_ + e];
        atomicAdd(&cnt[c0], 1); atomicAdd(&gbc[(c0 >> 8) * 8 + g], 1);
    } else if (gid < ETOT_) {
        int e = gid - ER_ - ES_;
        int c0 = B_HA + eh[EH_ + e];
        int c1 = B_HI + eh[e];
        atomicAdd(&cnt[c0], 1); atomicAdd(&gbc[(c0 >> 8) * 8 + g], 1);
        atomicAdd(&cnt[c1], 1); atomicAdd(&gbc[(c1 >> 8) * 8 + g], 1);
    }
}

__global__ __launch_bounds__(256) void bsum_kernel(const int* __restrict__ cnt, int n,
                                                   int* __restrict__ bsum) {
    int b = blockIdx.x, t = threadIdx.x;
    long i0 = (long)b * 1024 + t * 4;
    int s = 0;
    if (i0 + 4 <= n) {
        int4 v = *(const int4*)&cnt[i0];
        s = v.x + v.y + v.z + v.w;
    } else {
#pragma unroll
        for (int k = 0; k < 4; ++k)
            if (i0 + k < n) s += cnt[i0 + k];
    }
#pragma unroll
    for (int d = 32; d; d >>= 1) s += __shfl_down(s, d);
    __shared__ int ws[4];
    if ((t & 63) == 0) ws[t >> 6] = s;
    __syncthreads();
    if (t == 0) bsum[b] = ws[0] + ws[1] + ws[2] + ws[3];
}

// single block, 256 threads, scans nb <= 256 chunk totals -> exclusive
__global__ __launch_bounds__(256) void scan_top_kernel(int* __restrict__ bsum, int nb) {
    int t = threadIdx.x;
    int v = (t < nb) ? bsum[t] : 0;
    int incl = v;
    int lane = t & 63;
#pragma unroll
    for (int d = 1; d < 64; d <<= 1) {
        int u = __shfl_up(incl, d);
        if (lane >= d) incl += u;
    }
    __shared__ int wt[4];
    if (lane == 63) wt[t >> 6] = incl;
    __syncthreads();
    int add = 0;
    for (int i = 0; i < (t >> 6); ++i) add += wt[i];
    if (t < nb) bsum[t] = incl - v + add;
}

// INCL=true: off1[i] = inclusive prefix (bucket END); INCL=false: exclusive (START)
template <bool INCL>
__global__ __launch_bounds__(256) void scan_block_kernel(const int* __restrict__ cnt, int n,
                                                         const int* __restrict__ bexcl,
                                                         int* __restrict__ off1) {
    int b = blockIdx.x, t = threadIdx.x;
    long i0 = (long)b * 1024 + t * 4;
    int e0 = 0, e1 = 0, e2 = 0, e3 = 0;
    if (i0 + 4 <= n) {
        int4 v = *(const int4*)&cnt[i0];
        e0 = v.x; e1 = v.y; e2 = v.z; e3 = v.w;
    } else {
        if (i0 < n) e0 = cnt[i0];
        if (i0 + 1 < n) e1 = cnt[i0 + 1];
        if (i0 + 2 < n) e2 = cnt[i0 + 2];
        if (i0 + 3 < n) e3 = cnt[i0 + 3];
    }
    int tsum = e0 + e1 + e2 + e3;
    int incl = tsum;
    int lane = t & 63;
#pragma unroll
    for (int d = 1; d < 64; d <<= 1) {
        int u = __shfl_up(incl, d);
        if (lane >= d) incl += u;
    }
    __shared__ int wt[4];
    if (lane == 63) wt[t >> 6] = incl;
    __syncthreads();
    int w = t >> 6, wo = 0;
    for (int i = 0; i < w; ++i) wo += wt[i];
    int ex = incl - tsum + wo + bexcl[b];
    if (INCL) {
        if (i0 < n) off1[i0] = ex + e0;
        if (i0 + 1 < n) off1[i0 + 1] = ex + e0 + e1;
        if (i0 + 2 < n) off1[i0 + 2] = ex + e0 + e1 + e2;
        if (i0 + 3 < n) off1[i0 + 3] = ex + tsum;
    } else {
        if (i0 < n) off1[i0] = ex;
        if (i0 + 1 < n) off1[i0 + 1] = ex + e0;
        if (i0 + 2 < n) off1[i0 + 2] = ex + e0 + e1;
        if (i0 + 3 < n) off1[i0 + 3] = ex + e0 + e1 + e2;
    }
}

// pass A: scatter packed records into per-(bucket, xcd-group) regions of cpool.
// rec = (node&255)<<17 | val  (val < 2^17). rc1 cursors mutate -> region ends.
__global__ __launch_bounds__(256) void fillA_kernel(const int* __restrict__ er,
                                                    const int* __restrict__ es,
                                                    const int* __restrict__ eh,
                                                    int* __restrict__ rc1,
                                                    int* __restrict__ cpool) {
    int g = blockIdx.x & 7;
    int gid = blockIdx.x * 256 + threadIdx.x;
    if (gid < ER_) {
        int u = er[gid], it = er[ER_ + gid];
        int c0 = B_RI + it, c1 = B_RU + u;
        cpool[atomicAdd(&rc1[(c0 >> 8) * 8 + g], 1)] = ((c0 & 255) << 17) | u;
        cpool[atomicAdd(&rc1[(c1 >> 8) * 8 + g], 1)] = ((c1 & 255) << 17) | it;
    } else if (gid < ER_ + ES_) {
        int e = gid - ER_;
        int c0 = B_SI + es[ES_ + e];
        cpool[atomicAdd(&rc1[(c0 >> 8) * 8 + g], 1)] = ((c0 & 255) << 17) | es[e];
    } else if (gid < ETOT_) {
        int e = gid - ER_ - ES_;
        int c0 = B_HA + eh[EH_ + e];
        int c1 = B_HI + eh[e];
        cpool[atomicAdd(&rc1[(c0 >> 8) * 8 + g], 1)] = ((c0 & 255) << 17) | eh[e];
        cpool[atomicAdd(&rc1[(c1 >> 8) * 8 + g], 1)] = ((c1 & 255) << 17) | eh[EH_ + e];
    }
}

// pass B: one block per coarse bucket; place records to final CSR positions
// via LDS per-node cursors. Writes land in a dense ~12KB pool window.
__global__ __launch_bounds__(256) void fillB_kernel(const int* __restrict__ cpool,
                                                    const int* __restrict__ rc1,
                                                    const int* __restrict__ off1,
                                                    int* __restrict__ pool) {
    __shared__ int cur[256];
    int b = blockIdx.x, t = threadIdx.x;
    int node = b * 256 + t;
    cur[t] = (node < NTOT_) ? off1[node - 1] : 0;   // start of node (off1 = ends)
    __syncthreads();
    int lo = rc1[b * 8 - 1];   // sentinel-safe: end of previous bucket's last region
    int hi = rc1[b * 8 + 7];
    for (int j = lo + t; j < hi; j += 256) {
        int rec = cpool[j];
        int pos = atomicAdd(&cur[rec >> 17], 1);
        pool[pos] = rec & 0x1FFFF;
    }
}

#define ACC8(A, V)                                                            \
    {                                                                         \
        A[0] += bf2f((u16)(V.x & 0xffff)); A[1] += bf2f((u16)(V.x >> 16));    \
        A[2] += bf2f((u16)(V.y & 0xffff)); A[3] += bf2f((u16)(V.y >> 16));    \
        A[4] += bf2f((u16)(V.z & 0xffff)); A[5] += bf2f((u16)(V.z >> 16));    \
        A[6] += bf2f((u16)(V.w & 0xffff)); A[7] += bf2f((u16)(V.w >> 16));    \
    }

// gather-mean over bf16 features: 16 lanes per dst row, 16B (8 cols) per lane.
// off1 holds inclusive ends; off1[row-1] (sentinel-safe) is the start.
__global__ __launch_bounds__(256) void gatherb_kernel(const u16* __restrict__ feat,
                                                      const int* __restrict__ off1,
                                                      const int* __restrict__ pool,
                                                      int n,
                                                      u16* __restrict__ agg) {
    int row = blockIdx.x * 16 + (threadIdx.x >> 4);
    if (row >= n) return;
    int lane = (threadIdx.x & 15) * 8;
    int start = off1[row - 1];
    int end = off1[row];
    float a0[8], a1[8], a2[8], a3[8];
#pragma unroll
    for (int k = 0; k < 8; ++k) { a0[k] = 0.f; a1[k] = 0.f; a2[k] = 0.f; a3[k] = 0.f; }
    int j = start;
    for (; j + 4 <= end; j += 4) {
        int s0 = pool[j], s1 = pool[j + 1], s2 = pool[j + 2], s3 = pool[j + 3];
        uint4 v0 = *(const uint4*)&feat[(i64)s0 * H_ + lane];
        uint4 v1 = *(const uint4*)&feat[(i64)s1 * H_ + lane];
        uint4 v2 = *(const uint4*)&feat[(i64)s2 * H_ + lane];
        uint4 v3 = *(const uint4*)&feat[(i64)s3 * H_ + lane];
        ACC8(a0, v0); ACC8(a1, v1); ACC8(a2, v2); ACC8(a3, v3);
    }
    for (; j < end; ++j) {
        int s0 = pool[j];
        uint4 v0 = *(const uint4*)&feat[(i64)s0 * H_ + lane];
        ACC8(a0, v0);
    }
    float inv = 1.0f / fmaxf((float)(end - start), 1.0f);
    uint4 o;
    float r0, r1;
    r0 = (a0[0] + a1[0] + a2[0] + a3[0]) * inv; r1 = (a0[1] + a1[1] + a2[1] + a3[1]) * inv;
    o.x = (u32)f2bf(r0) | ((u32)f2bf(r1) << 16);
    r0 = (a0[2] + a1[2] + a2[2] + a3[2]) * inv; r1 = (a0[3] + a1[3] + a2[3] + a3[3]) * inv;
    o.y = (u32)f2bf(r0) | ((u32)f2bf(r1) << 16);
    r0 = (a0[4] + a1[4] + a2[4] + a3[4]) * inv; r1 = (a0[5] + a1[5] + a2[5] + a3[5]) * inv;
    o.z = (u32)f2bf(r0) | ((u32)f2bf(r1) << 16);
    r0 = (a0[6] + a1[6] + a2[6] + a3[6]) * inv; r1 = (a0[7] + a1[7] + a2[7] + a3[7]) * inv;
    o.w = (u32)f2bf(r0) | ((u32)f2bf(r1) << 16);
    *(uint4*)&agg[(i64)row * H_ + lane] = o;
}

// ---- weight prep: W (fp32 [K][128], optionally sum of 3) -> frag-tiled hi/lo bf16 ----
// frag layout: index = ((kc*8 + nt)*64 + l)*8 + e  holds  W_T[n=nt*16+(l&15)][k=kc*32+((l>>4)<<3)+e]
struct WJob {
    const float* s0; const float* s1; const float* s2;
    int logK; int base;
};
struct WJobs { WJob j[17]; };

__global__ __launch_bounds__(256) void wsplit_kernel(WJobs jobs, int njobs, int total,
                                                     u16* __restrict__ WTH,
                                                     u16* __restrict__ WTL) {
    int gid = blockIdx.x * 256 + threadIdx.x;
    if (gid >= total) return;
    int ji = 0;
    for (int i = 1; i < 17; ++i)
        if (i < njobs && gid >= jobs.j[i].base) ji = i;
    WJob jb = jobs.j[ji];
    int local = gid - jb.base;
    int e = local & 7;
    int l = (local >> 3) & 63;
    int nt = (local >> 9) & 7;
    int kc = local >> 12;
    int n = nt * 16 + (l & 15);
    int k = kc * 32 + ((l >> 4) << 3) + e;
    i64 si = (i64)k * 128 + n;
    float v = jb.s0[si];
    if (jb.s1 != nullptr) v += jb.s1[si] + jb.s2[si];
    u32 b = __float_as_uint(v);
    u16 h = (u16)(b >> 16);                       // truncation split: v = hi + lo
    float rem = v - __uint_as_float(b & 0xffff0000u);
    WTH[gid] = h;
    WTL[gid] = (u16)(__float_as_uint(rem) >> 16);
}

// ---- x_item GEMM: fp32 A (xif, K=256), 3-term hi/lo split, bf16 output only ----
__device__ __forceinline__ void split8(const float* f, bf16x8& h, bf16x8& lo) {
#pragma unroll
    for (int i = 0; i < 8; ++i) {
        u32 b = __float_as_uint(f[i]);
        h[i] = (short)(u16)(b >> 16);
        float rem = f[i] - __uint_as_float(b & 0xffff0000u);
        lo[i] = (short)(u16)(__float_as_uint(rem) >> 16);
    }
}

__global__ __launch_bounds__(256) void mgemm_x_kernel(
    const float* __restrict__ A, const u16* __restrict__ Wh, const u16* __restrict__ Wl,
    const float* __restrict__ bias, u16* __restrict__ Cbf, int M) {
    int t = threadIdx.x;
    int w = t >> 6, l = t & 63;
    int lr = l & 15, lq = l >> 4;
    int m0 = blockIdx.x * 128 + w * 32;

    f32x4 acc[2][8];
#pragma unroll
    for (int mt = 0; mt < 2; ++mt)
#pragma unroll
        for (int nt = 0; nt < 8; ++nt) acc[mt][nt] = (f32x4){0.f, 0.f, 0.f, 0.f};

    for (int kc = 0; kc < 8; ++kc) {   // K = 256
        bf16x8 ah0, al0, ah1, al1;
        {
            int row = m0 + lr;
            float f[8];
            if (row < M) {
                const float* ap = &A[(i64)row * FEAT_ + kc * 32 + lq * 8];
                *(float4*)&f[0] = *(const float4*)ap;
                *(float4*)&f[4] = *(const float4*)(ap + 4);
            } else {
#pragma unroll
                for (int i = 0; i < 8; ++i) f[i] = 0.f;
            }
            split8(f, ah0, al0);
        }
        {
            int row = m0 + 16 + lr;
            float f[8];
            if (row < M) {
                const float* ap = &A[(i64)row * FEAT_ + kc * 32 + lq * 8];
                *(float4*)&f[0] = *(const float4*)ap;
                *(float4*)&f[4] = *(const float4*)(ap + 4);
            } else {
#pragma unroll
                for (int i = 0; i < 8; ++i) f[i] = 0.f;
            }
            split8(f, ah1, al1);
        }
        const u16* whp = Wh + ((i64)kc * 8) * 512 + (i64)l * 8;
        const u16* wlp = Wl + ((i64)kc * 8) * 512 + (i64)l * 8;
#pragma unroll
        for (int nt = 0; nt < 8; ++nt) {
            bf16x8 bh = *(const bf16x8*)(whp + nt * 512);
            bf16x8 bl = *(const bf16x8*)(wlp + nt * 512);
            acc[0][nt] = __builtin_amdgcn_mfma_f32_16x16x32_bf16(ah0, bh, acc[0][nt], 0, 0, 0);
            acc[1][nt] = __builtin_amdgcn_mfma_f32_16x16x32_bf16(ah1, bh, acc[1][nt], 0, 0, 0);
            acc[0][nt] = __builtin_amdgcn_mfma_f32_16x16x32_bf16(al0, bh, acc[0][nt], 0, 0, 0);
            acc[1][nt] = __builtin_amdgcn_mfma_f32_16x16x32_bf16(al1, bh, acc[1][nt], 0, 0, 0);
            acc[0][nt] = __builtin_amdgcn_mfma_f32_16x16x32_bf16(ah0, bl, acc[0][nt], 0, 0, 0);
            acc[1][nt] = __builtin_amdgcn_mfma_f32_16x16x32_bf16(ah1, bl, acc[1][nt], 0, 0, 0);
        }
    }
#pragma unroll
    for (int nt = 0; nt < 8; ++nt) {
        int col = nt * 16 + lr;
        float bb = bias[col];
#pragma unroll
        for (int mt = 0; mt < 2; ++mt) {
#pragma unroll
            for (int r = 0; r < 4; ++r) {
                int row = m0 + mt * 16 + (lq << 2) + r;
                if (row < M) Cbf[(i64)row * H_ + col] = f2bf(acc[mt][nt][r] + bb);
            }
        }
    }
}

// ---- dual GEMM, bf16 A operands (K=128 each), 2-term W split ----
__global__ __launch_bounds__(256) void mgemm_d_kernel(
    const u16* __restrict__ A1, const u16* __restrict__ W1h, const u16* __restrict__ W1l,
    const u16* __restrict__ A2, const u16* __restrict__ W2h, const u16* __restrict__ W2l,
    const float* __restrict__ b1, const float* __restrict__ b2,
    float* __restrict__ C, u16* __restrict__ Cbf, int M) {
    int t = threadIdx.x;
    int w = t >> 6, l = t & 63;
    int lr = l & 15, lq = l >> 4;
    int m0 = blockIdx.x * 128 + w * 32;

    f32x4 acc[2][8];
#pragma unroll
    for (int mt = 0; mt < 2; ++mt)
#pragma unroll
        for (int nt = 0; nt < 8; ++nt) acc[mt][nt] = (f32x4){0.f, 0.f, 0.f, 0.f};

#pragma unroll
    for (int mat = 0; mat < 2; ++mat) {
        const u16* A = mat ? A2 : A1;
        const u16* Wh = mat ? W2h : W1h;
        const u16* Wl = mat ? W2l : W1l;
#pragma unroll
        for (int kc = 0; kc < 4; ++kc) {   // K = 128
            bf16x8 a0 = {0, 0, 0, 0, 0, 0, 0, 0}, a1 = {0, 0, 0, 0, 0, 0, 0, 0};
            int row0 = m0 + lr, row1 = m0 + 16 + lr;
            if (row0 < M) a0 = *(const bf16x8*)&A[(i64)row0 * H_ + kc * 32 + lq * 8];
            if (row1 < M) a1 = *(const bf16x8*)&A[(i64)row1 * H_ + kc * 32 + lq * 8];
            const u16* whp = Wh + ((i64)kc * 8) * 512 + (i64)l * 8;
            const u16* wlp = Wl + ((i64)kc * 8) * 512 + (i64)l * 8;
#pragma unroll
            for (int nt = 0; nt < 8; ++nt) {
                bf16x8 bh = *(const bf16x8*)(whp + nt * 512);
                bf16x8 bl = *(const bf16x8*)(wlp + nt * 512);
                acc[0][nt] = __builtin_amdgcn_mfma_f32_16x16x32_bf16(a0, bh, acc[0][nt], 0, 0, 0);
                acc[1][nt] = __builtin_amdgcn_mfma_f32_16x16x32_bf16(a1, bh, acc[1][nt], 0, 0, 0);
                acc[0][nt] = __builtin_amdgcn_mfma_f32_16x16x32_bf16(a0, bl, acc[0][nt], 0, 0, 0);
                acc[1][nt] = __builtin_amdgcn_mfma_f32_16x16x32_bf16(a1, bl, acc[1][nt], 0, 0, 0);
            }
        }
    }
#pragma unroll
    for (int nt = 0; nt < 8; ++nt) {
        int col = nt * 16 + lr;
        float bb = 0.5f * (b1[col] + b2[col]);
#pragma unroll
        for (int mt = 0; mt < 2; ++mt) {
#pragma unroll
            for (int r = 0; r < 4; ++r) {
                int row = m0 + mt * 16 + (lq << 2) + r;
                if (row < M) {
                    float o = fmaxf(0.5f * acc[mt][nt][r] + bb, 0.f);
                    if (C != nullptr) C[(i64)row * H_ + col] = o;
                    if (Cbf != nullptr) Cbf[(i64)row * H_ + col] = f2bf(o);
                }
            }
        }
    }
}

__global__ __launch_bounds__(256) void fuse_kernel(const float* __restrict__ alpha,
                                                   const float* __restrict__ hui,
                                                   const float* __restrict__ hii,
                                                   const float* __restrict__ hia,
                                                   float* __restrict__ fused,
                                                   float* __restrict__ wout) {
    long i = (long)blockIdx.x * 256 + threadIdx.x;
    float a0 = alpha[0], a1 = alpha[1], a2 = alpha[2];
    float mx = fmaxf(a0, fmaxf(a1, a2));
    float e0 = expf(a0 - mx), e1 = expf(a1 - mx), e2 = expf(a2 - mx);
    float inv = 1.f / (e0 + e1 + e2);
    float w0 = e0 * inv, w1 = e1 * inv, w2 = e2 * inv;
    if (i == 0) { wout[0] = w0; wout[1] = w1; wout[2] = w2; }
    long n4 = (long)NI_ * H_ / 4;
    if (i < n4) {
        float4 u = ((const float4*)hui)[i];
        float4 v = ((const float4*)hii)[i];
        float4 t = ((const float4*)hia)[i];
        float4 o;
        o.x = w0 * u.x + w1 * v.x + w2 * t.x;
        o.y = w0 * u.y + w1 * v.y + w2 * t.y;
        o.z = w0 * u.z + w1 * v.z + w2 * t.z;
        o.w = w0 * u.w + w1 * v.w + w2 * t.w;
        ((float4*)fused)[i] = o;
    }
}

extern "C" void kernel_launch(void* const* d_in, const int* in_sizes, int n_in,
                              void* d_out, int out_size, void* d_ws, size_t ws_size,
                              hipStream_t stream) {
    const float* xif  = (const float*)d_in[0];
    const float* uemb = (const float*)d_in[1];
    const float* aemb = (const float*)d_in[2];
    const float* liW  = (const float*)d_in[3];
    const float* lib  = (const float*)d_in[4];
    const float* uiWl = (const float*)d_in[5];
    const float* uibl = (const float*)d_in[6];
    const float* uiWr = (const float*)d_in[7];
    const float* iiWl = (const float*)d_in[8];
    const float* iibl = (const float*)d_in[9];
    const float* iiWr = (const float*)d_in[10];
    const float* iaWl = (const float*)d_in[11];
    const float* iabl = (const float*)d_in[12];
    const float* iaWr = (const float*)d_in[13];
    const float* alpha = (const float*)d_in[14];
    const int* er = (const int*)d_in[15];
    const int* es = (const int*)d_in[16];
    const int* eh = (const int*)d_in[17];

    float* out = (float*)d_out;
    float* FUSED  = out;
    float* OUT_UI = out + (i64)NI_ * H_;
    float* OUT_II = out + (i64)2 * NI_ * H_;
    float* OUT_IA = out + (i64)3 * NI_ * H_;
    float* WOUT   = out + (i64)4 * NI_ * H_;

    // ---- workspace layout: bf16 region first (16B-aligned), then ints ----
    u16* u = (u16*)d_ws;
    i64 uo = 0;
    u16* WTH    = u + uo; uo += 294912;
    u16* WTL    = u + uo; uo += 294912;
    u16* X_bf   = u + uo; uo += (i64)NI_ * H_;
    u16* HI1_bf = u + uo; uo += (i64)NI_ * H_;
    u16* HU1_bf = u + uo; uo += (i64)NU_ * H_;
    u16* HA1_bf = u + uo; uo += (i64)NA_ * H_;
    u16* AGG_bf = u + uo; uo += (i64)NU_ * H_;
    u16* UE_bf  = u + uo; uo += (i64)NU_ * H_;
    u16* AE_bf  = u + uo; uo += (i64)NA_ * H_;

    int* ip = (int*)(u + uo);
    i64 io = 0;
    int* OFF   = ip + io; io += NTOT_ + 4;   // [0]=sentinel; off1 = OFF+1 (inclusive ends)
    int* CNT   = ip + io; io += NTOT_;       // node degrees
    int* GBC   = ip + io; io += 8000;        // (bucket, group) counts (GB_=7976)
    int* RCarr = ip + io; io += 8000;        // [0]=sentinel; rc1 = RCarr+1 (region cursors)
    int* POOL  = ip + io; io += ETOT_ + ER_ + EH_;   // 3,000,000 final CSR vals
    int* CPOOL = ip + io; io += ETOT_ + ER_ + EH_;   // 3,000,000 staged records
    int* BSUM  = ip + io; io += 256;
    int* off1 = OFF + 1;
    int* rc1  = RCarr + 1;

    // ---- CSR build: count -> scans -> XCD-local staged scatter -> bucket place ----
    {
        long nz = (NTOT_ + 4) + NTOT_ + 8000 + 8000;   // OFF+CNT+GBC+RCarr, /4 exact
        fillz_kernel<<<(int)((nz / 4 + 255) / 256), 256, 0, stream>>>((float4*)OFF, nz / 4);
        countall_kernel<<<(ETOT_ + 255) / 256, 256, 0, stream>>>(er, es, eh, CNT, GBC);
        int nb = (NTOT_ + 1023) / 1024;                // 250
        bsum_kernel<<<nb, 256, 0, stream>>>(CNT, NTOT_, BSUM);
        scan_top_kernel<<<1, 256, 0, stream>>>(BSUM, nb);
        scan_block_kernel<true><<<nb, 256, 0, stream>>>(CNT, NTOT_, BSUM, off1);
        int nbg = (GB_ + 1023) / 1024;                 // 8
        bsum_kernel<<<nbg, 256, 0, stream>>>(GBC, GB_, BSUM);
        scan_top_kernel<<<1, 256, 0, stream>>>(BSUM, nbg);
        scan_block_kernel<false><<<nbg, 256, 0, stream>>>(GBC, GB_, BSUM, rc1);
        fillA_kernel<<<(ETOT_ + 255) / 256, 256, 0, stream>>>(er, es, eh, rc1, CPOOL);
        fillB_kernel<<<NB_, 256, 0, stream>>>(CPOOL, rc1, off1, POOL);
    }

    // ---- weight split/transpose ----
    const float* famWl[8] = {uiWl, uiWl, uiWl, iiWl, iiWl, iaWl, iaWl, iaWl};
    const float* famWr[8] = {uiWr, uiWr, uiWr, iiWr, iiWr, iaWr, iaWr, iaWr};
    const float* famBl[8] = {uibl, uibl, uibl, iibl, iibl, iabl, iabl, iabl};
    const int eidx[8] = {0, 1, 4, 0, 2, 0, 1, 5};
    const int sidx[8] = {3, 2, 7, 1, 3, 3, 2, 6};

    WJobs jobs;
    jobs.j[0] = {liW, nullptr, nullptr, 8, 0};
    int base = 32768;
    for (int s = 0; s < 8; ++s) {
        jobs.j[1 + 2 * s] = {famWl[s] + (i64)eidx[s] * 16384, nullptr, nullptr, 7, base};
        base += 16384;
        jobs.j[2 + 2 * s] = {famWr[s] + (i64)eidx[s] * 16384,
                             famWl[s] + (i64)sidx[s] * 16384,
                             famWr[s] + (i64)sidx[s] * 16384, 7, base};
        base += 16384;
    }
    wsplit_kernel<<<(base + 255) / 256, 256, 0, stream>>>(jobs, 17, base, WTH, WTL);

    // ---- bf16 copies of input embedding tables ----
    tobf_kernel<<<((NU_ * H_ / 4) + 255) / 256, 256, 0, stream>>>(
        (const float4*)uemb, (ushort4*)UE_bf, (long)NU_ * H_ / 4);
    tobf_kernel<<<((NA_ * H_ / 4) + 255) / 256, 256, 0, stream>>>(
        (const float4*)aemb, (ushort4*)AE_bf, (long)NA_ * H_ / 4);

    // x_item = xif @ liW + lib  -> bf16 table
    mgemm_x_kernel<<<(NI_ + 127) / 128, 256, 0, stream>>>(xif, WTH, WTL, lib, X_bf, NI_);

    auto gath = [&](const u16* feat, int cbase, int ndst) {
        gatherb_kernel<<<(ndst + 15) / 16, 256, 0, stream>>>(feat, off1 + cbase, POOL, ndst, AGG_bf);
    };
    auto gemm2 = [&](int slot, const u16* A2m, float* Cout, u16* Cbfout, int M) {
        const u16* w1h = WTH + 32768 + (i64)(2 * slot) * 16384;
        const u16* w1l = WTL + 32768 + (i64)(2 * slot) * 16384;
        const u16* w2h = WTH + 32768 + (i64)(2 * slot + 1) * 16384;
        const u16* w2l = WTL + 32768 + (i64)(2 * slot + 1) * 16384;
        const float* be = famBl[slot] + (i64)eidx[slot] * 128;
        const float* bs = famBl[slot] + (i64)sidx[slot] * 128;
        mgemm_d_kernel<<<(M + 127) / 128, 256, 0, stream>>>(
            AGG_bf, w1h, w1l, A2m, w2h, w2l, be, bs, Cout, Cbfout, M);
    };

    // ---- UI branch ----
    gath(UE_bf, B_RI, NI_);
    gemm2(0, X_bf, nullptr, HI1_bf, NI_);
    gath(X_bf, B_RU, NU_);
    gemm2(1, UE_bf, nullptr, HU1_bf, NU_);
    gath(HU1_bf, B_RI, NI_);                 // L1 o_i only (o_u dead)
    gemm2(2, HI1_bf, OUT_UI, nullptr, NI_);

    // ---- II branch ----
    gath(X_bf, B_SI, NI_);
    gemm2(3, X_bf, nullptr, HI1_bf, NI_);
    gath(HI1_bf, B_SI, NI_);
    gemm2(4, HI1_bf, OUT_II, nullptr, NI_);

    // ---- IA branch ----
    gath(X_bf, B_HA, NA_);
    gemm2(5, AE_bf, nullptr, HA1_bf, NA_);
    gath(AE_bf, B_HI, NI_);
    gemm2(6, X_bf, nullptr, HI1_bf, NI_);
    gath(HA1_bf, B_HI, NI_);                 // L1 o_i only (o_a dead)
    gemm2(7, HI1_bf, OUT_IA, nullptr, NI_);

    // ---- fuse ----
    long n4 = (long)NI_ * H_ / 4;
    fuse_kernel<<<(int)((n4 + 255) / 256), 256, 0, stream>>>(
        alpha, OUT_UI, OUT_II, OUT_IA, FUSED, WOUT);
}

// Round 8
// 1247.734 us; speedup vs baseline: 1.3420x; 1.3420x over previous
//
#include <hip/hip_runtime.h>

#define NU_ 100000
#define NI_ 50000
#define NA_ 5000
#define FEAT_ 256
#define H_ 128
#define ER_ 1000000
#define ES_ 500000
#define EH_ 250000

#define NTOT_ (3 * NI_ + NU_ + NA_)      // 255000 combined counters
#define ETOT_ (ER_ + ES_ + EH_)          // 1,750,000 edges
#define NB_ ((NTOT_ + 255) / 256)        // 997 coarse buckets (256 nodes each)
#define GB_ (NB_ * 8)                    // 7976 (g-major) regions
// counter-array bases (order defines pool layout via global scan)
#define B_RI 0
#define B_RU (NI_)
#define B_SI (NI_ + NU_)
#define B_HA (2 * NI_ + NU_)
#define B_HI (2 * NI_ + NU_ + NA_)

typedef long long i64;
typedef unsigned short u16;
typedef unsigned int u32;
typedef __attribute__((ext_vector_type(8))) short bf16x8;
typedef __attribute__((ext_vector_type(4))) float f32x4;

__device__ __forceinline__ u16 f2bf(float v) {           // round-to-nearest-even
    u32 b = __float_as_uint(v);
    b += 0x7fff + ((b >> 16) & 1);
    return (u16)(b >> 16);
}
__device__ __forceinline__ float bf2f(u16 v) {
    return __uint_as_float((u32)v << 16);
}

__global__ __launch_bounds__(256) void fillz_kernel(float4* __restrict__ p, long n4) {
    long i = (long)blockIdx.x * 256 + threadIdx.x;
    if (i < n4) p[i] = make_float4(0.f, 0.f, 0.f, 0.f);
}

// fp32 -> bf16 table convert
__global__ __launch_bounds__(256) void tobf_kernel(const float4* __restrict__ in,
                                                   ushort4* __restrict__ out, long n4) {
    long i = (long)blockIdx.x * 256 + threadIdx.x;
    if (i >= n4) return;
    float4 v = in[i];
    ushort4 o;
    o.x = f2bf(v.x); o.y = f2bf(v.y); o.z = f2bf(v.z); o.w = f2bf(v.w);
    out[i] = o;
}

// ---- fused degree + region counts over all 5 graphs ----
// g = blockIdx&7 ~ XCD under round-robin dispatch. gbc is G-MAJOR (g*NB_+bucket):
// each 4KB group-slab is touched by exactly one XCD -> atomic lines stay in
// that XCD's L2 (bucket-major interleaving caused cross-XCD line ping-pong).
__global__ __launch_bounds__(256) void countall_kernel(const int* __restrict__ er,
                                                       const int* __restrict__ es,
                                                       const int* __restrict__ eh,
                                                       int* __restrict__ cnt,
                                                       int* __restrict__ gbc) {
    int gb = (blockIdx.x & 7) * NB_;
    int gid = blockIdx.x * 256 + threadIdx.x;
    if (gid < ER_) {
        int c0 = B_RI + er[ER_ + gid];
        int c1 = B_RU + er[gid];
        atomicAdd(&cnt[c0], 1); atomicAdd(&gbc[gb + (c0 >> 8)], 1);
        atomicAdd(&cnt[c1], 1); atomicAdd(&gbc[gb + (c1 >> 8)], 1);
    } else if (gid < ER_ + ES_) {
        int e = gid - ER_;
        int c0 = B_SI + es[ES_ + e];
        atomicAdd(&cnt[c0], 1); atomicAdd(&gbc[gb + (c0 >> 8)], 1);
    } else if (gid < ETOT_) {
        int e = gid - ER_ - ES_;
        int c0 = B_HA + eh[EH_ + e];
        int c1 = B_HI + eh[e];
        atomicAdd(&cnt[c0], 1); atomicAdd(&gbc[gb + (c0 >> 8)], 1);
        atomicAdd(&cnt[c1], 1); atomicAdd(&gbc[gb + (c1 >> 8)], 1);
    }
}

__global__ __launch_bounds__(256) void bsum_kernel(const int* __restrict__ cnt, int n,
                                                   int* __restrict__ bsum) {
    int b = blockIdx.x, t = threadIdx.x;
    long i0 = (long)b * 1024 + t * 4;
    int s = 0;
    if (i0 + 4 <= n) {
        int4 v = *(const int4*)&cnt[i0];
        s = v.x + v.y + v.z + v.w;
    } else {
#pragma unroll
        for (int k = 0; k < 4; ++k)
            if (i0 + k < n) s += cnt[i0 + k];
    }
#pragma unroll
    for (int d = 32; d; d >>= 1) s += __shfl_down(s, d);
    __shared__ int ws[4];
    if ((t & 63) == 0) ws[t >> 6] = s;
    __syncthreads();
    if (t == 0) bsum[b] = ws[0] + ws[1] + ws[2] + ws[3];
}

// single block, 256 threads, scans nb <= 256 chunk totals -> exclusive
__global__ __launch_bounds__(256) void scan_top_kernel(int* __restrict__ bsum, int nb) {
    int t = threadIdx.x;
    int v = (t < nb) ? bsum[t] : 0;
    int incl = v;
    int lane = t & 63;
#pragma unroll
    for (int d = 1; d < 64; d <<= 1) {
        int u = __shfl_up(incl, d);
        if (lane >= d) incl += u;
    }
    __shared__ int wt[4];
    if (lane == 63) wt[t >> 6] = incl;
    __syncthreads();
    int add = 0;
    for (int i = 0; i < (t >> 6); ++i) add += wt[i];
    if (t < nb) bsum[t] = incl - v + add;
}

// INCL=true: off1[i] = inclusive prefix (bucket END); INCL=false: exclusive (START)
template <bool INCL>
__global__ __launch_bounds__(256) void scan_block_kernel(const int* __restrict__ cnt, int n,
                                                         const int* __restrict__ bexcl,
                                                         int* __restrict__ off1) {
    int b = blockIdx.x, t = threadIdx.x;
    long i0 = (long)b * 1024 + t * 4;
    int e0 = 0, e1 = 0, e2 = 0, e3 = 0;
    if (i0 + 4 <= n) {
        int4 v = *(const int4*)&cnt[i0];
        e0 = v.x; e1 = v.y; e2 = v.z; e3 = v.w;
    } else {
        if (i0 < n) e0 = cnt[i0];
        if (i0 + 1 < n) e1 = cnt[i0 + 1];
        if (i0 + 2 < n) e2 = cnt[i0 + 2];
        if (i0 + 3 < n) e3 = cnt[i0 + 3];
    }
    int tsum = e0 + e1 + e2 + e3;
    int incl = tsum;
    int lane = t & 63;
#pragma unroll
    for (int d = 1; d < 64; d <<= 1) {
        int u = __shfl_up(incl, d);
        if (lane >= d) incl += u;
    }
    __shared__ int wt[4];
    if (lane == 63) wt[t >> 6] = incl;
    __syncthreads();
    int w = t >> 6, wo = 0;
    for (int i = 0; i < w; ++i) wo += wt[i];
    int ex = incl - tsum + wo + bexcl[b];
    if (INCL) {
        if (i0 < n) off1[i0] = ex + e0;
        if (i0 + 1 < n) off1[i0 + 1] = ex + e0 + e1;
        if (i0 + 2 < n) off1[i0 + 2] = ex + e0 + e1 + e2;
        if (i0 + 3 < n) off1[i0 + 3] = ex + tsum;
    } else {
        if (i0 < n) off1[i0] = ex;
        if (i0 + 1 < n) off1[i0 + 1] = ex + e0;
        if (i0 + 2 < n) off1[i0 + 2] = ex + e0 + e1;
        if (i0 + 3 < n) off1[i0 + 3] = ex + e0 + e1 + e2;
    }
}

// pass A: scatter packed records into per-(g, bucket) regions of cpool (g-major).
// rec = (node&255)<<17 | val  (val < 2^17). rc1 cursors mutate -> region ends.
// Each XCD appends into its private ~1.5MB slab -> lines coalesce in its L2.
__global__ __launch_bounds__(256) void fillA_kernel(const int* __restrict__ er,
                                                    const int* __restrict__ es,
                                                    const int* __restrict__ eh,
                                                    int* __restrict__ rc1,
                                                    int* __restrict__ cpool) {
    int gb = (blockIdx.x & 7) * NB_;
    int gid = blockIdx.x * 256 + threadIdx.x;
    if (gid < ER_) {
        int u = er[gid], it = er[ER_ + gid];
        int c0 = B_RI + it, c1 = B_RU + u;
        cpool[atomicAdd(&rc1[gb + (c0 >> 8)], 1)] = ((c0 & 255) << 17) | u;
        cpool[atomicAdd(&rc1[gb + (c1 >> 8)], 1)] = ((c1 & 255) << 17) | it;
    } else if (gid < ER_ + ES_) {
        int e = gid - ER_;
        int c0 = B_SI + es[ES_ + e];
        cpool[atomicAdd(&rc1[gb + (c0 >> 8)], 1)] = ((c0 & 255) << 17) | es[e];
    } else if (gid < ETOT_) {
        int e = gid - ER_ - ES_;
        int c0 = B_HA + eh[EH_ + e];
        int c1 = B_HI + eh[e];
        cpool[atomicAdd(&rc1[gb + (c0 >> 8)], 1)] = ((c0 & 255) << 17) | eh[e];
        cpool[atomicAdd(&rc1[gb + (c1 >> 8)], 1)] = ((c1 & 255) << 17) | eh[EH_ + e];
    }
}

// pass B: one block per coarse bucket; read the bucket's 8 g-spans, place
// records to final CSR positions via LDS per-node cursors (dense ~12KB window).
__global__ __launch_bounds__(256) void fillB_kernel(const int* __restrict__ cpool,
                                                    const int* __restrict__ rc1,
                                                    const int* __restrict__ off1,
                                                    int* __restrict__ pool) {
    __shared__ int cur[256];
    int b = blockIdx.x, t = threadIdx.x;
    int node = b * 256 + t;
    cur[t] = (node < NTOT_) ? off1[node - 1] : 0;   // start of node (off1 = ends)
    __syncthreads();
#pragma unroll
    for (int g = 0; g < 8; ++g) {
        int idx = g * NB_ + b;
        int lo = rc1[idx - 1];   // sentinel-safe: end of previous region = our start
        int hi = rc1[idx];
        for (int j = lo + t; j < hi; j += 256) {
            int rec = cpool[j];
            int pos = atomicAdd(&cur[rec >> 17], 1);
            pool[pos] = rec & 0x1FFFF;
        }
    }
}

#define ACC8(A, V)                                                            \
    {                                                                         \
        A[0] += bf2f((u16)(V.x & 0xffff)); A[1] += bf2f((u16)(V.x >> 16));    \
        A[2] += bf2f((u16)(V.y & 0xffff)); A[3] += bf2f((u16)(V.y >> 16));    \
        A[4] += bf2f((u16)(V.z & 0xffff)); A[5] += bf2f((u16)(V.z >> 16));    \
        A[6] += bf2f((u16)(V.w & 0xffff)); A[7] += bf2f((u16)(V.w >> 16));    \
    }

// gather-mean over bf16 features: 16 lanes per dst row, 16B (8 cols) per lane.
// off1 holds inclusive ends; off1[row-1] (sentinel-safe) is the start.
__global__ __launch_bounds__(256) void gatherb_kernel(const u16* __restrict__ feat,
                                                      const int* __restrict__ off1,
                                                      const int* __restrict__ pool,
                                                      int n,
                                                      u16* __restrict__ agg) {
    int row = blockIdx.x * 16 + (threadIdx.x >> 4);
    if (row >= n) return;
    int lane = (threadIdx.x & 15) * 8;
    int start = off1[row - 1];
    int end = off1[row];
    float a0[8], a1[8], a2[8], a3[8];
#pragma unroll
    for (int k = 0; k < 8; ++k) { a0[k] = 0.f; a1[k] = 0.f; a2[k] = 0.f; a3[k] = 0.f; }
    int j = start;
    for (; j + 4 <= end; j += 4) {
        int s0 = pool[j], s1 = pool[j + 1], s2 = pool[j + 2], s3 = pool[j + 3];
        uint4 v0 = *(const uint4*)&feat[(i64)s0 * H_ + lane];
        uint4 v1 = *(const uint4*)&feat[(i64)s1 * H_ + lane];
        uint4 v2 = *(const uint4*)&feat[(i64)s2 * H_ + lane];
        uint4 v3 = *(const uint4*)&feat[(i64)s3 * H_ + lane];
        ACC8(a0, v0); ACC8(a1, v1); ACC8(a2, v2); ACC8(a3, v3);
    }
    for (; j < end; ++j) {
        int s0 = pool[j];
        uint4 v0 = *(const uint4*)&feat[(i64)s0 * H_ + lane];
        ACC8(a0, v0);
    }
    float inv = 1.0f / fmaxf((float)(end - start), 1.0f);
    uint4 o;
    float r0, r1;
    r0 = (a0[0] + a1[0] + a2[0] + a3[0]) * inv; r1 = (a0[1] + a1[1] + a2[1] + a3[1]) * inv;
    o.x = (u32)f2bf(r0) | ((u32)f2bf(r1) << 16);
    r0 = (a0[2] + a1[2] + a2[2] + a3[2]) * inv; r1 = (a0[3] + a1[3] + a2[3] + a3[3]) * inv;
    o.y = (u32)f2bf(r0) | ((u32)f2bf(r1) << 16);
    r0 = (a0[4] + a1[4] + a2[4] + a3[4]) * inv; r1 = (a0[5] + a1[5] + a2[5] + a3[5]) * inv;
    o.z = (u32)f2bf(r0) | ((u32)f2bf(r1) << 16);
    r0 = (a0[6] + a1[6] + a2[6] + a3[6]) * inv; r1 = (a0[7] + a1[7] + a2[7] + a3[7]) * inv;
    o.w = (u32)f2bf(r0) | ((u32)f2bf(r1) << 16);
    *(uint4*)&agg[(i64)row * H_ + lane] = o;
}

// ---- weight prep: W (fp32 [K][128], optionally sum of 3) -> frag-tiled hi/lo bf16 ----
// frag layout: index = ((kc*8 + nt)*64 + l)*8 + e  holds  W_T[n=nt*16+(l&15)][k=kc*32+((l>>4)<<3)+e]
struct WJob {
    const float* s0; const float* s1; const float* s2;
    int logK; int base;
};
struct WJobs { WJob j[17]; };

__global__ __launch_bounds__(256) void wsplit_kernel(WJobs jobs, int njobs, int total,
                                                     u16* __restrict__ WTH,
                                                     u16* __restrict__ WTL) {
    int gid = blockIdx.x * 256 + threadIdx.x;
    if (gid >= total) return;
    int ji = 0;
    for (int i = 1; i < 17; ++i)
        if (i < njobs && gid >= jobs.j[i].base) ji = i;
    WJob jb = jobs.j[ji];
    int local = gid - jb.base;
    int e = local & 7;
    int l = (local >> 3) & 63;
    int nt = (local >> 9) & 7;
    int kc = local >> 12;
    int n = nt * 16 + (l & 15);
    int k = kc * 32 + ((l >> 4) << 3) + e;
    i64 si = (i64)k * 128 + n;
    float v = jb.s0[si];
    if (jb.s1 != nullptr) v += jb.s1[si] + jb.s2[si];
    u32 b = __float_as_uint(v);
    u16 h = (u16)(b >> 16);                       // truncation split: v = hi + lo
    float rem = v - __uint_as_float(b & 0xffff0000u);
    WTH[gid] = h;
    WTL[gid] = (u16)(__float_as_uint(rem) >> 16);
}

// ---- x_item GEMM: fp32 A (xif, K=256), 3-term hi/lo split, bf16 output only ----
__device__ __forceinline__ void split8(const float* f, bf16x8& h, bf16x8& lo) {
#pragma unroll
    for (int i = 0; i < 8; ++i) {
        u32 b = __float_as_uint(f[i]);
        h[i] = (short)(u16)(b >> 16);
        float rem = f[i] - __uint_as_float(b & 0xffff0000u);
        lo[i] = (short)(u16)(__float_as_uint(rem) >> 16);
    }
}

__global__ __launch_bounds__(256) void mgemm_x_kernel(
    const float* __restrict__ A, const u16* __restrict__ Wh, const u16* __restrict__ Wl,
    const float* __restrict__ bias, u16* __restrict__ Cbf, int M) {
    int t = threadIdx.x;
    int w = t >> 6, l = t & 63;
    int lr = l & 15, lq = l >> 4;
    int m0 = blockIdx.x * 128 + w * 32;

    f32x4 acc[2][8];
#pragma unroll
    for (int mt = 0; mt < 2; ++mt)
#pragma unroll
        for (int nt = 0; nt < 8; ++nt) acc[mt][nt] = (f32x4){0.f, 0.f, 0.f, 0.f};

    for (int kc = 0; kc < 8; ++kc) {   // K = 256
        bf16x8 ah0, al0, ah1, al1;
        {
            int row = m0 + lr;
            float f[8];
            if (row < M) {
                const float* ap = &A[(i64)row * FEAT_ + kc * 32 + lq * 8];
                *(float4*)&f[0] = *(const float4*)ap;
                *(float4*)&f[4] = *(const float4*)(ap + 4);
            } else {
#pragma unroll
                for (int i = 0; i < 8; ++i) f[i] = 0.f;
            }
            split8(f, ah0, al0);
        }
        {
            int row = m0 + 16 + lr;
            float f[8];
            if (row < M) {
                const float* ap = &A[(i64)row * FEAT_ + kc * 32 + lq * 8];
                *(float4*)&f[0] = *(const float4*)ap;
                *(float4*)&f[4] = *(const float4*)(ap + 4);
            } else {
#pragma unroll
                for (int i = 0; i < 8; ++i) f[i] = 0.f;
            }
            split8(f, ah1, al1);
        }
        const u16* whp = Wh + ((i64)kc * 8) * 512 + (i64)l * 8;
        const u16* wlp = Wl + ((i64)kc * 8) * 512 + (i64)l * 8;
#pragma unroll
        for (int nt = 0; nt < 8; ++nt) {
            bf16x8 bh = *(const bf16x8*)(whp + nt * 512);
            bf16x8 bl = *(const bf16x8*)(wlp + nt * 512);
            acc[0][nt] = __builtin_amdgcn_mfma_f32_16x16x32_bf16(ah0, bh, acc[0][nt], 0, 0, 0);
            acc[1][nt] = __builtin_amdgcn_mfma_f32_16x16x32_bf16(ah1, bh, acc[1][nt], 0, 0, 0);
            acc[0][nt] = __builtin_amdgcn_mfma_f32_16x16x32_bf16(al0, bh, acc[0][nt], 0, 0, 0);
            acc[1][nt] = __builtin_amdgcn_mfma_f32_16x16x32_bf16(al1, bh, acc[1][nt], 0, 0, 0);
            acc[0][nt] = __builtin_amdgcn_mfma_f32_16x16x32_bf16(ah0, bl, acc[0][nt], 0, 0, 0);
            acc[1][nt] = __builtin_amdgcn_mfma_f32_16x16x32_bf16(ah1, bl, acc[1][nt], 0, 0, 0);
        }
    }
#pragma unroll
    for (int nt = 0; nt < 8; ++nt) {
        int col = nt * 16 + lr;
        float bb = bias[col];
#pragma unroll
        for (int mt = 0; mt < 2; ++mt) {
#pragma unroll
            for (int r = 0; r < 4; ++r) {
                int row = m0 + mt * 16 + (lq << 2) + r;
                if (row < M) Cbf[(i64)row * H_ + col] = f2bf(acc[mt][nt][r] + bb);
            }
        }
    }
}

// ---- dual GEMM, bf16 A operands (K=128 each), 2-term W split ----
__global__ __launch_bounds__(256) void mgemm_d_kernel(
    const u16* __restrict__ A1, const u16* __restrict__ W1h, const u16* __restrict__ W1l,
    const u16* __restrict__ A2, const u16* __restrict__ W2h, const u16* __restrict__ W2l,
    const float* __restrict__ b1, const float* __restrict__ b2,
    float* __restrict__ C, u16* __restrict__ Cbf, int M) {
    int t = threadIdx.x;
    int w = t >> 6, l = t & 63;
    int lr = l & 15, lq = l >> 4;
    int m0 = blockIdx.x * 128 + w * 32;

    f32x4 acc[2][8];
#pragma unroll
    for (int mt = 0; mt < 2; ++mt)
#pragma unroll
        for (int nt = 0; nt < 8; ++nt) acc[mt][nt] = (f32x4){0.f, 0.f, 0.f, 0.f};

#pragma unroll
    for (int mat = 0; mat < 2; ++mat) {
        const u16* A = mat ? A2 : A1;
        const u16* Wh = mat ? W2h : W1h;
        const u16* Wl = mat ? W2l : W1l;
#pragma unroll
        for (int kc = 0; kc < 4; ++kc) {   // K = 128
            bf16x8 a0 = {0, 0, 0, 0, 0, 0, 0, 0}, a1 = {0, 0, 0, 0, 0, 0, 0, 0};
            int row0 = m0 + lr, row1 = m0 + 16 + lr;
            if (row0 < M) a0 = *(const bf16x8*)&A[(i64)row0 * H_ + kc * 32 + lq * 8];
            if (row1 < M) a1 = *(const bf16x8*)&A[(i64)row1 * H_ + kc * 32 + lq * 8];
            const u16* whp = Wh + ((i64)kc * 8) * 512 + (i64)l * 8;
            const u16* wlp = Wl + ((i64)kc * 8) * 512 + (i64)l * 8;
#pragma unroll
            for (int nt = 0; nt < 8; ++nt) {
                bf16x8 bh = *(const bf16x8*)(whp + nt * 512);
                bf16x8 bl = *(const bf16x8*)(wlp + nt * 512);
                acc[0][nt] = __builtin_amdgcn_mfma_f32_16x16x32_bf16(a0, bh, acc[0][nt], 0, 0, 0);
                acc[1][nt] = __builtin_amdgcn_mfma_f32_16x16x32_bf16(a1, bh, acc[1][nt], 0, 0, 0);
                acc[0][nt] = __builtin_amdgcn_mfma_f32_16x16x32_bf16(a0, bl, acc[0][nt], 0, 0, 0);
                acc[1][nt] = __builtin_amdgcn_mfma_f32_16x16x32_bf16(a1, bl, acc[1][nt], 0, 0, 0);
            }
        }
    }
#pragma unroll
    for (int nt = 0; nt < 8; ++nt) {
        int col = nt * 16 + lr;
        float bb = 0.5f * (b1[col] + b2[col]);
#pragma unroll
        for (int mt = 0; mt < 2; ++mt) {
#pragma unroll
            for (int r = 0; r < 4; ++r) {
                int row = m0 + mt * 16 + (lq << 2) + r;
                if (row < M) {
                    float o = fmaxf(0.5f * acc[mt][nt][r] + bb, 0.f);
                    if (C != nullptr) C[(i64)row * H_ + col] = o;
                    if (Cbf != nullptr) Cbf[(i64)row * H_ + col] = f2bf(o);
                }
            }
        }
    }
}

__global__ __launch_bounds__(256) void fuse_kernel(const float* __restrict__ alpha,
                                                   const float* __restrict__ hui,
                                                   const float* __restrict__ hii,
                                                   const float* __restrict__ hia,
                                                   float* __restrict__ fused,
                                                   float* __restrict__ wout) {
    long i = (long)blockIdx.x * 256 + threadIdx.x;
    float a0 = alpha[0], a1 = alpha[1], a2 = alpha[2];
    float mx = fmaxf(a0, fmaxf(a1, a2));
    float e0 = expf(a0 - mx), e1 = expf(a1 - mx), e2 = expf(a2 - mx);
    float inv = 1.f / (e0 + e1 + e2);
    float w0 = e0 * inv, w1 = e1 * inv, w2 = e2 * inv;
    if (i == 0) { wout[0] = w0; wout[1] = w1; wout[2] = w2; }
    long n4 = (long)NI_ * H_ / 4;
    if (i < n4) {
        float4 u = ((const float4*)hui)[i];
        float4 v = ((const float4*)hii)[i];
        float4 t = ((const float4*)hia)[i];
        float4 o;
        o.x = w0 * u.x + w1 * v.x + w2 * t.x;
        o.y = w0 * u.y + w1 * v.y + w2 * t.y;
        o.z = w0 * u.z + w1 * v.z + w2 * t.z;
        o.w = w0 * u.w + w1 * v.w + w2 * t.w;
        ((float4*)fused)[i] = o;
    }
}

extern "C" void kernel_launch(void* const* d_in, const int* in_sizes, int n_in,
                              void* d_out, int out_size, void* d_ws, size_t ws_size,
                              hipStream_t stream) {
    const float* xif  = (const float*)d_in[0];
    const float* uemb = (const float*)d_in[1];
    const float* aemb = (const float*)d_in[2];
    const float* liW  = (const float*)d_in[3];
    const float* lib  = (const float*)d_in[4];
    const float* uiWl = (const float*)d_in[5];
    const float* uibl = (const float*)d_in[6];
    const float* uiWr = (const float*)d_in[7];
    const float* iiWl = (const float*)d_in[8];
    const float* iibl = (const float*)d_in[9];
    const float* iiWr = (const float*)d_in[10];
    const float* iaWl = (const float*)d_in[11];
    const float* iabl = (const float*)d_in[12];
    const float* iaWr = (const float*)d_in[13];
    const float* alpha = (const float*)d_in[14];
    const int* er = (const int*)d_in[15];
    const int* es = (const int*)d_in[16];
    const int* eh = (const int*)d_in[17];

    float* out = (float*)d_out;
    float* FUSED  = out;
    float* OUT_UI = out + (i64)NI_ * H_;
    float* OUT_II = out + (i64)2 * NI_ * H_;
    float* OUT_IA = out + (i64)3 * NI_ * H_;
    float* WOUT   = out + (i64)4 * NI_ * H_;

    // ---- workspace layout: bf16 region first (16B-aligned), then ints ----
    u16* u = (u16*)d_ws;
    i64 uo = 0;
    u16* WTH    = u + uo; uo += 294912;
    u16* WTL    = u + uo; uo += 294912;
    u16* X_bf   = u + uo; uo += (i64)NI_ * H_;
    u16* HI1_bf = u + uo; uo += (i64)NI_ * H_;
    u16* HU1_bf = u + uo; uo += (i64)NU_ * H_;
    u16* HA1_bf = u + uo; uo += (i64)NA_ * H_;
    u16* AGG_bf = u + uo; uo += (i64)NU_ * H_;
    u16* UE_bf  = u + uo; uo += (i64)NU_ * H_;
    u16* AE_bf  = u + uo; uo += (i64)NA_ * H_;

    int* ip = (int*)(u + uo);
    i64 io = 0;
    int* OFF   = ip + io; io += NTOT_ + 4;   // [0]=sentinel; off1 = OFF+1 (inclusive ends)
    int* CNT   = ip + io; io += NTOT_;       // node degrees
    int* GBC   = ip + io; io += 8000;        // (g, bucket) counts, g-major (GB_=7976)
    int* RCarr = ip + io; io += 8000;        // [0]=sentinel; rc1 = RCarr+1 (region cursors)
    int* POOL  = ip + io; io += ETOT_ + ER_ + EH_;   // 3,000,000 final CSR vals
    int* CPOOL = ip + io; io += ETOT_ + ER_ + EH_;   // 3,000,000 staged records
    int* BSUM  = ip + io; io += 256;
    int* off1 = OFF + 1;
    int* rc1  = RCarr + 1;

    // ---- CSR build: count -> scans -> XCD-local staged scatter -> bucket place ----
    {
        long nz = (NTOT_ + 4) + NTOT_ + 8000 + 8000;   // OFF+CNT+GBC+RCarr, /4 exact
        fillz_kernel<<<(int)((nz / 4 + 255) / 256), 256, 0, stream>>>((float4*)OFF, nz / 4);
        countall_kernel<<<(ETOT_ + 255) / 256, 256, 0, stream>>>(er, es, eh, CNT, GBC);
        int nb = (NTOT_ + 1023) / 1024;                // 250
        bsum_kernel<<<nb, 256, 0, stream>>>(CNT, NTOT_, BSUM);
        scan_top_kernel<<<1, 256, 0, stream>>>(BSUM, nb);
        scan_block_kernel<true><<<nb, 256, 0, stream>>>(CNT, NTOT_, BSUM, off1);
        int nbg = (GB_ + 1023) / 1024;                 // 8
        bsum_kernel<<<nbg, 256, 0, stream>>>(GBC, GB_, BSUM);
        scan_top_kernel<<<1, 256, 0, stream>>>(BSUM, nbg);
        scan_block_kernel<false><<<nbg, 256, 0, stream>>>(GBC, GB_, BSUM, rc1);
        fillA_kernel<<<(ETOT_ + 255) / 256, 256, 0, stream>>>(er, es, eh, rc1, CPOOL);
        fillB_kernel<<<NB_, 256, 0, stream>>>(CPOOL, rc1, off1, POOL);
    }

    // ---- weight split/transpose ----
    const float* famWl[8] = {uiWl, uiWl, uiWl, iiWl, iiWl, iaWl, iaWl, iaWl};
    const float* famWr[8] = {uiWr, uiWr, uiWr, iiWr, iiWr, iaWr, iaWr, iaWr};
    const float* famBl[8] = {uibl, uibl, uibl, iibl, iibl, iabl, iabl, iabl};
    const int eidx[8] = {0, 1, 4, 0, 2, 0, 1, 5};
    const int sidx[8] = {3, 2, 7, 1, 3, 3, 2, 6};

    WJobs jobs;
    jobs.j[0] = {liW, nullptr, nullptr, 8, 0};
    int base = 32768;
    for (int s = 0; s < 8; ++s) {
        jobs.j[1 + 2 * s] = {famWl[s] + (i64)eidx[s] * 16384, nullptr, nullptr, 7, base};
        base += 16384;
        jobs.j[2 + 2 * s] = {famWr[s] + (i64)eidx[s] * 16384,
                             famWl[s] + (i64)sidx[s] * 16384,
                             famWr[s] + (i64)sidx[s] * 16384, 7, base};
        base += 16384;
    }
    wsplit_kernel<<<(base + 255) / 256, 256, 0, stream>>>(jobs, 17, base, WTH, WTL);

    // ---- bf16 copies of input embedding tables ----
    tobf_kernel<<<((NU_ * H_ / 4) + 255) / 256, 256, 0, stream>>>(
        (const float4*)uemb, (ushort4*)UE_bf, (long)NU_ * H_ / 4);
    tobf_kernel<<<((NA_ * H_ / 4) + 255) / 256, 256, 0, stream>>>(
        (const float4*)aemb, (ushort4*)AE_bf, (long)NA_ * H_ / 4);

    // x_item = xif @ liW + lib  -> bf16 table
    mgemm_x_kernel<<<(NI_ + 127) / 128, 256, 0, stream>>>(xif, WTH, WTL, lib, X_bf, NI_);

    auto gath = [&](const u16* feat, int cbase, int ndst) {
        gatherb_kernel<<<(ndst + 15) / 16, 256, 0, stream>>>(feat, off1 + cbase, POOL, ndst, AGG_bf);
    };
    auto gemm2 = [&](int slot, const u16* A2m, float* Cout, u16* Cbfout, int M) {
        const u16* w1h = WTH + 32768 + (i64)(2 * slot) * 16384;
        const u16* w1l = WTL + 32768 + (i64)(2 * slot) * 16384;
        const u16* w2h = WTH + 32768 + (i64)(2 * slot + 1) * 16384;
        const u16* w2l = WTL + 32768 + (i64)(2 * slot + 1) * 16384;
        const float* be = famBl[slot] + (i64)eidx[slot] * 128;
        const float* bs = famBl[slot] + (i64)sidx[slot] * 128;
        mgemm_d_kernel<<<(M + 127) / 128, 256, 0, stream>>>(
            AGG_bf, w1h, w1l, A2m, w2h, w2l, be, bs, Cout, Cbfout, M);
    };

    // ---- UI branch ----
    gath(UE_bf, B_RI, NI_);
    gemm2(0, X_bf, nullptr, HI1_bf, NI_);
    gath(X_bf, B_RU, NU_);
    gemm2(1, UE_bf, nullptr, HU1_bf, NU_);
    gath(HU1_bf, B_RI, NI_);                 // L1 o_i only (o_u dead)
    gemm2(2, HI1_bf, OUT_UI, nullptr, NI_);

    // ---- II branch ----
    gath(X_bf, B_SI, NI_);
    gemm2(3, X_bf, nullptr, HI1_bf, NI_);
    gath(HI1_bf, B_SI, NI_);
    gemm2(4, HI1_bf, OUT_II, nullptr, NI_);

    // ---- IA branch ----
    gath(X_bf, B_HA, NA_);
    gemm2(5, AE_bf, nullptr, HA1_bf, NA_);
    gath(AE_bf, B_HI, NI_);
    gemm2(6, X_bf, nullptr, HI1_bf, NI_);
    gath(HA1_bf, B_HI, NI_);                 // L1 o_i only (o_a dead)
    gemm2(7, HI1_bf, OUT_IA, nullptr, NI_);

    // ---- fuse ----
    long n4 = (long)NI_ * H_ / 4;
    fuse_kernel<<<(int)((n4 + 255) / 256), 256, 0, stream>>>(
        alpha, OUT_UI, OUT_II, OUT_IA, FUSED, WOUT);
}

// Round 9
// 667.155 us; speedup vs baseline: 2.5098x; 1.8702x over previous
//
#include <hip/hip_runtime.h>

#define NU_ 100000
#define NI_ 50000
#define NA_ 5000
#define FEAT_ 256
#define H_ 128
#define ER_ 1000000
#define ES_ 500000
#define EH_ 250000

#define NTOT_ (3 * NI_ + NU_ + NA_)      // 255000 combined nodes
#define RTOT_ (2 * ER_ + ES_ + 2 * EH_)  // 3,000,000 records
#define NSB_ ((NTOT_ + 1023) / 1024)     // 250 super-buckets (1024 nodes each)
// node-space bases (order defines pool layout)
#define B_RI 0
#define B_RU (NI_)
#define B_SI (NI_ + NU_)
#define B_HA (2 * NI_ + NU_)
#define B_HI (2 * NI_ + NU_ + NA_)

typedef long long i64;
typedef unsigned short u16;
typedef unsigned int u32;
typedef __attribute__((ext_vector_type(8))) short bf16x8;
typedef __attribute__((ext_vector_type(4))) float f32x4;

__device__ __forceinline__ u16 f2bf(float v) {           // round-to-nearest-even
    u32 b = __float_as_uint(v);
    b += 0x7fff + ((b >> 16) & 1);
    return (u16)(b >> 16);
}
__device__ __forceinline__ float bf2f(u16 v) {
    return __uint_as_float((u32)v << 16);
}

__global__ __launch_bounds__(256) void fillz_kernel(float4* __restrict__ p, long n4) {
    long i = (long)blockIdx.x * 256 + threadIdx.x;
    if (i < n4) p[i] = make_float4(0.f, 0.f, 0.f, 0.f);
}

// fp32 -> bf16 table convert
__global__ __launch_bounds__(256) void tobf_kernel(const float4* __restrict__ in,
                                                   ushort4* __restrict__ out, long n4) {
    long i = (long)blockIdx.x * 256 + threadIdx.x;
    if (i >= n4) return;
    float4 v = in[i];
    ushort4 o;
    o.x = f2bf(v.x); o.y = f2bf(v.y); o.z = f2bf(v.z); o.w = f2bf(v.w);
    out[i] = o;
}

// record r -> (node, val). val < 2^17 (ids < 100000), node < 255000.
__device__ __forceinline__ void rec_of(int r, const int* __restrict__ er,
                                       const int* __restrict__ es,
                                       const int* __restrict__ eh,
                                       int& node, int& val) {
    if (r < 2 * ER_) {
        int e = r >> 1;
        if ((r & 1) == 0) { node = B_RI + er[ER_ + e]; val = er[e]; }
        else              { node = B_RU + er[e];       val = er[ER_ + e]; }
    } else if (r < 2 * ER_ + ES_) {
        int e = r - 2 * ER_;
        node = B_SI + es[ES_ + e]; val = es[e];
    } else {
        int q = r - 2 * ER_ - ES_;
        int e = q >> 1;
        if ((q & 1) == 0) { node = B_HA + eh[EH_ + e]; val = eh[e]; }
        else              { node = B_HI + eh[e];       val = eh[EH_ + e]; }
    }
}

// ---- pass 1: per-block LDS histogram over super-buckets, global add ----
__global__ __launch_bounds__(256) void histo_kernel(const int* __restrict__ er,
                                                    const int* __restrict__ es,
                                                    const int* __restrict__ eh,
                                                    int* __restrict__ sbt) {
    __shared__ int h[256];
    int t = threadIdx.x;
    h[t] = 0;
    __syncthreads();
    int base = blockIdx.x * 4096;
#pragma unroll
    for (int i = 0; i < 16; ++i) {
        int r = base + i * 256 + t;
        if (r < RTOT_) {
            int node, val;
            rec_of(r, er, es, eh, node, val);
            atomicAdd(&h[node >> 10], 1);
        }
    }
    __syncthreads();
    if (t < NSB_ && h[t] > 0) atomicAdd(&sbt[t], h[t]);
}

// ---- pass 2: one block scans the 250 SB totals -> SBB (bases) + SBC (cursors) ----
__global__ __launch_bounds__(256) void sbscan_kernel(const int* __restrict__ sbt,
                                                     int* __restrict__ sbb,
                                                     int* __restrict__ sbc) {
    int t = threadIdx.x;
    int v = (t < NSB_) ? sbt[t] : 0;
    int incl = v;
    int lane = t & 63;
#pragma unroll
    for (int d = 1; d < 64; d <<= 1) {
        int u = __shfl_up(incl, d);
        if (lane >= d) incl += u;
    }
    __shared__ int wsum[4];
    if (lane == 63) wsum[t >> 6] = incl;
    __syncthreads();
    int wo = 0;
    for (int i = 0; i < (t >> 6); ++i) wo += wsum[i];
    int ex = wo + incl - v;
    if (t < NSB_) { sbb[t] = ex; sbc[t] = ex; }
}

// ---- pass 3: LDS-binned scatter. One global atomic per (block, SB); records
// written as contiguous runs into the SB's region of cpool (coalesced). ----
__global__ __launch_bounds__(256) void binA_kernel(const int* __restrict__ er,
                                                   const int* __restrict__ es,
                                                   const int* __restrict__ eh,
                                                   int* __restrict__ sbc,
                                                   int* __restrict__ cpool) {
    __shared__ int h[256];
    __shared__ int gof[256];
    int t = threadIdx.x;
    h[t] = 0;
    __syncthreads();
    int base = blockIdx.x * 4096;
    int sbs[16];
    u32 recs[16];
#pragma unroll
    for (int i = 0; i < 16; ++i) {
        int r = base + i * 256 + t;
        sbs[i] = -1;
        if (r < RTOT_) {
            int node, val;
            rec_of(r, er, es, eh, node, val);
            int sb = node >> 10;
            sbs[i] = sb;
            recs[i] = ((u32)(node & 1023) << 17) | (u32)val;
            atomicAdd(&h[sb], 1);
        }
    }
    __syncthreads();
    if (t < 256) {
        int c = h[t];
        if (c > 0) gof[t] = atomicAdd(&sbc[t], c);
        h[t] = 0;   // reuse as block-local cursor
    }
    __syncthreads();
#pragma unroll
    for (int i = 0; i < 16; ++i) {
        if (sbs[i] >= 0) {
            int slot = atomicAdd(&h[sbs[i]], 1);
            cpool[gof[sbs[i]] + slot] = (int)recs[i];
        }
    }
}

// ---- pass 4: one block per SB. Dense span [SBB[sb], SBC[sb]) of cpool.
// LDS node histogram -> LDS scan -> write off1 (inclusive ends) -> place vals. ----
__global__ __launch_bounds__(256) void binB_kernel(const int* __restrict__ cpool,
                                                   const int* __restrict__ sbb,
                                                   const int* __restrict__ sbc,
                                                   int* __restrict__ off1,
                                                   int* __restrict__ pool) {
    __shared__ int c[1024];
    __shared__ int b[1024];
    __shared__ int wsum[4];
    int sb = blockIdx.x, t = threadIdx.x;
    int start = sbb[sb], end = sbc[sb];
#pragma unroll
    for (int k = 0; k < 4; ++k) c[t * 4 + k] = 0;
    __syncthreads();
    for (int j = start + t; j < end; j += 256)
        atomicAdd(&c[((u32)cpool[j]) >> 17], 1);
    __syncthreads();
    int t4 = t * 4;
    int s0 = c[t4], s1 = c[t4 + 1], s2 = c[t4 + 2], s3 = c[t4 + 3];
    int tsum = s0 + s1 + s2 + s3;
    int incl = tsum;
    int lane = t & 63;
#pragma unroll
    for (int d = 1; d < 64; d <<= 1) {
        int u = __shfl_up(incl, d);
        if (lane >= d) incl += u;
    }
    if (lane == 63) wsum[t >> 6] = incl;
    __syncthreads();
    int wo = 0;
    for (int i = 0; i < (t >> 6); ++i) wo += wsum[i];
    int ex = wo + incl - tsum;
    b[t4] = ex; b[t4 + 1] = ex + s0; b[t4 + 2] = ex + s0 + s1; b[t4 + 3] = ex + s0 + s1 + s2;
    __syncthreads();
#pragma unroll
    for (int k = 0; k < 4; ++k) {
        int i = t4 + k;
        int node = sb * 1024 + i;
        int bi = b[i];
        if (node < NTOT_) off1[node] = start + bi + c[i];   // inclusive end
        b[i] = start + bi;                                  // cursor
    }
    __syncthreads();
    for (int j = start + t; j < end; j += 256) {
        u32 rec = (u32)cpool[j];
        int pos = atomicAdd(&b[rec >> 17], 1);
        pool[pos] = (int)(rec & 0x1FFFF);
    }
}

#define ACC8(A, V)                                                            \
    {                                                                         \
        A[0] += bf2f((u16)(V.x & 0xffff)); A[1] += bf2f((u16)(V.x >> 16));    \
        A[2] += bf2f((u16)(V.y & 0xffff)); A[3] += bf2f((u16)(V.y >> 16));    \
        A[4] += bf2f((u16)(V.z & 0xffff)); A[5] += bf2f((u16)(V.z >> 16));    \
        A[6] += bf2f((u16)(V.w & 0xffff)); A[7] += bf2f((u16)(V.w >> 16));    \
    }

// gather-mean over bf16 features: 16 lanes per dst row, 16B (8 cols) per lane.
// off1 holds inclusive ends; off1[row-1] (sentinel-safe) is the start.
__global__ __launch_bounds__(256) void gatherb_kernel(const u16* __restrict__ feat,
                                                      const int* __restrict__ off1,
                                                      const int* __restrict__ pool,
                                                      int n,
                                                      u16* __restrict__ agg) {
    int row = blockIdx.x * 16 + (threadIdx.x >> 4);
    if (row >= n) return;
    int lane = (threadIdx.x & 15) * 8;
    int start = off1[row - 1];
    int end = off1[row];
    float a0[8], a1[8], a2[8], a3[8];
#pragma unroll
    for (int k = 0; k < 8; ++k) { a0[k] = 0.f; a1[k] = 0.f; a2[k] = 0.f; a3[k] = 0.f; }
    int j = start;
    for (; j + 4 <= end; j += 4) {
        int s0 = pool[j], s1 = pool[j + 1], s2 = pool[j + 2], s3 = pool[j + 3];
        uint4 v0 = *(const uint4*)&feat[(i64)s0 * H_ + lane];
        uint4 v1 = *(const uint4*)&feat[(i64)s1 * H_ + lane];
        uint4 v2 = *(const uint4*)&feat[(i64)s2 * H_ + lane];
        uint4 v3 = *(const uint4*)&feat[(i64)s3 * H_ + lane];
        ACC8(a0, v0); ACC8(a1, v1); ACC8(a2, v2); ACC8(a3, v3);
    }
    for (; j < end; ++j) {
        int s0 = pool[j];
        uint4 v0 = *(const uint4*)&feat[(i64)s0 * H_ + lane];
        ACC8(a0, v0);
    }
    float inv = 1.0f / fmaxf((float)(end - start), 1.0f);
    uint4 o;
    float r0, r1;
    r0 = (a0[0] + a1[0] + a2[0] + a3[0]) * inv; r1 = (a0[1] + a1[1] + a2[1] + a3[1]) * inv;
    o.x = (u32)f2bf(r0) | ((u32)f2bf(r1) << 16);
    r0 = (a0[2] + a1[2] + a2[2] + a3[2]) * inv; r1 = (a0[3] + a1[3] + a2[3] + a3[3]) * inv;
    o.y = (u32)f2bf(r0) | ((u32)f2bf(r1) << 16);
    r0 = (a0[4] + a1[4] + a2[4] + a3[4]) * inv; r1 = (a0[5] + a1[5] + a2[5] + a3[5]) * inv;
    o.z = (u32)f2bf(r0) | ((u32)f2bf(r1) << 16);
    r0 = (a0[6] + a1[6] + a2[6] + a3[6]) * inv; r1 = (a0[7] + a1[7] + a2[7] + a3[7]) * inv;
    o.w = (u32)f2bf(r0) | ((u32)f2bf(r1) << 16);
    *(uint4*)&agg[(i64)row * H_ + lane] = o;
}

// ---- weight prep: W (fp32 [K][128], optionally sum of 3) -> frag-tiled hi/lo bf16 ----
// frag layout: index = ((kc*8 + nt)*64 + l)*8 + e  holds  W_T[n=nt*16+(l&15)][k=kc*32+((l>>4)<<3)+e]
struct WJob {
    const float* s0; const float* s1; const float* s2;
    int logK; int base;
};
struct WJobs { WJob j[17]; };

__global__ __launch_bounds__(256) void wsplit_kernel(WJobs jobs, int njobs, int total,
                                                     u16* __restrict__ WTH,
                                                     u16* __restrict__ WTL) {
    int gid = blockIdx.x * 256 + threadIdx.x;
    if (gid >= total) return;
    int ji = 0;
    for (int i = 1; i < 17; ++i)
        if (i < njobs && gid >= jobs.j[i].base) ji = i;
    WJob jb = jobs.j[ji];
    int local = gid - jb.base;
    int e = local & 7;
    int l = (local >> 3) & 63;
    int nt = (local >> 9) & 7;
    int kc = local >> 12;
    int n = nt * 16 + (l & 15);
    int k = kc * 32 + ((l >> 4) << 3) + e;
    i64 si = (i64)k * 128 + n;
    float v = jb.s0[si];
    if (jb.s1 != nullptr) v += jb.s1[si] + jb.s2[si];
    u32 b = __float_as_uint(v);
    u16 h = (u16)(b >> 16);                       // truncation split: v = hi + lo
    float rem = v - __uint_as_float(b & 0xffff0000u);
    WTH[gid] = h;
    WTL[gid] = (u16)(__float_as_uint(rem) >> 16);
}

// ---- x_item GEMM: fp32 A (xif, K=256), 3-term hi/lo split, bf16 output only ----
__device__ __forceinline__ void split8(const float* f, bf16x8& h, bf16x8& lo) {
#pragma unroll
    for (int i = 0; i < 8; ++i) {
        u32 b = __float_as_uint(f[i]);
        h[i] = (short)(u16)(b >> 16);
        float rem = f[i] - __uint_as_float(b & 0xffff0000u);
        lo[i] = (short)(u16)(__float_as_uint(rem) >> 16);
    }
}

__global__ __launch_bounds__(256) void mgemm_x_kernel(
    const float* __restrict__ A, const u16* __restrict__ Wh, const u16* __restrict__ Wl,
    const float* __restrict__ bias, u16* __restrict__ Cbf, int M) {
    int t = threadIdx.x;
    int w = t >> 6, l = t & 63;
    int lr = l & 15, lq = l >> 4;
    int m0 = blockIdx.x * 128 + w * 32;

    f32x4 acc[2][8];
#pragma unroll
    for (int mt = 0; mt < 2; ++mt)
#pragma unroll
        for (int nt = 0; nt < 8; ++nt) acc[mt][nt] = (f32x4){0.f, 0.f, 0.f, 0.f};

    for (int kc = 0; kc < 8; ++kc) {   // K = 256
        bf16x8 ah0, al0, ah1, al1;
        {
            int row = m0 + lr;
            float f[8];
            if (row < M) {
                const float* ap = &A[(i64)row * FEAT_ + kc * 32 + lq * 8];
                *(float4*)&f[0] = *(const float4*)ap;
                *(float4*)&f[4] = *(const float4*)(ap + 4);
            } else {
#pragma unroll
                for (int i = 0; i < 8; ++i) f[i] = 0.f;
            }
            split8(f, ah0, al0);
        }
        {
            int row = m0 + 16 + lr;
            float f[8];
            if (row < M) {
                const float* ap = &A[(i64)row * FEAT_ + kc * 32 + lq * 8];
                *(float4*)&f[0] = *(const float4*)ap;
                *(float4*)&f[4] = *(const float4*)(ap + 4);
            } else {
#pragma unroll
                for (int i = 0; i < 8; ++i) f[i] = 0.f;
            }
            split8(f, ah1, al1);
        }
        const u16* whp = Wh + ((i64)kc * 8) * 512 + (i64)l * 8;
        const u16* wlp = Wl + ((i64)kc * 8) * 512 + (i64)l * 8;
#pragma unroll
        for (int nt = 0; nt < 8; ++nt) {
            bf16x8 bh = *(const bf16x8*)(whp + nt * 512);
            bf16x8 bl = *(const bf16x8*)(wlp + nt * 512);
            acc[0][nt] = __builtin_amdgcn_mfma_f32_16x16x32_bf16(ah0, bh, acc[0][nt], 0, 0, 0);
            acc[1][nt] = __builtin_amdgcn_mfma_f32_16x16x32_bf16(ah1, bh, acc[1][nt], 0, 0, 0);
            acc[0][nt] = __builtin_amdgcn_mfma_f32_16x16x32_bf16(al0, bh, acc[0][nt], 0, 0, 0);
            acc[1][nt] = __builtin_amdgcn_mfma_f32_16x16x32_bf16(al1, bh, acc[1][nt], 0, 0, 0);
            acc[0][nt] = __builtin_amdgcn_mfma_f32_16x16x32_bf16(ah0, bl, acc[0][nt], 0, 0, 0);
            acc[1][nt] = __builtin_amdgcn_mfma_f32_16x16x32_bf16(ah1, bl, acc[1][nt], 0, 0, 0);
        }
    }
#pragma unroll
    for (int nt = 0; nt < 8; ++nt) {
        int col = nt * 16 + lr;
        float bb = bias[col];
#pragma unroll
        for (int mt = 0; mt < 2; ++mt) {
#pragma unroll
            for (int r = 0; r < 4; ++r) {
                int row = m0 + mt * 16 + (lq << 2) + r;
                if (row < M) Cbf[(i64)row * H_ + col] = f2bf(acc[mt][nt][r] + bb);
            }
        }
    }
}

// ---- dual GEMM, bf16 A operands (K=128 each), 2-term W split ----
__global__ __launch_bounds__(256) void mgemm_d_kernel(
    const u16* __restrict__ A1, const u16* __restrict__ W1h, const u16* __restrict__ W1l,
    const u16* __restrict__ A2, const u16* __restrict__ W2h, const u16* __restrict__ W2l,
    const float* __restrict__ b1, const float* __restrict__ b2,
    float* __restrict__ C, u16* __restrict__ Cbf, int M) {
    int t = threadIdx.x;
    int w = t >> 6, l = t & 63;
    int lr = l & 15, lq = l >> 4;
    int m0 = blockIdx.x * 128 + w * 32;

    f32x4 acc[2][8];
#pragma unroll
    for (int mt = 0; mt < 2; ++mt)
#pragma unroll
        for (int nt = 0; nt < 8; ++nt) acc[mt][nt] = (f32x4){0.f, 0.f, 0.f, 0.f};

#pragma unroll
    for (int mat = 0; mat < 2; ++mat) {
        const u16* A = mat ? A2 : A1;
        const u16* Wh = mat ? W2h : W1h;
        const u16* Wl = mat ? W2l : W1l;
#pragma unroll
        for (int kc = 0; kc < 4; ++kc) {   // K = 128
            bf16x8 a0 = {0, 0, 0, 0, 0, 0, 0, 0}, a1 = {0, 0, 0, 0, 0, 0, 0, 0};
            int row0 = m0 + lr, row1 = m0 + 16 + lr;
            if (row0 < M) a0 = *(const bf16x8*)&A[(i64)row0 * H_ + kc * 32 + lq * 8];
            if (row1 < M) a1 = *(const bf16x8*)&A[(i64)row1 * H_ + kc * 32 + lq * 8];
            const u16* whp = Wh + ((i64)kc * 8) * 512 + (i64)l * 8;
            const u16* wlp = Wl + ((i64)kc * 8) * 512 + (i64)l * 8;
#pragma unroll
            for (int nt = 0; nt < 8; ++nt) {
                bf16x8 bh = *(const bf16x8*)(whp + nt * 512);
                bf16x8 bl = *(const bf16x8*)(wlp + nt * 512);
                acc[0][nt] = __builtin_amdgcn_mfma_f32_16x16x32_bf16(a0, bh, acc[0][nt], 0, 0, 0);
                acc[1][nt] = __builtin_amdgcn_mfma_f32_16x16x32_bf16(a1, bh, acc[1][nt], 0, 0, 0);
                acc[0][nt] = __builtin_amdgcn_mfma_f32_16x16x32_bf16(a0, bl, acc[0][nt], 0, 0, 0);
                acc[1][nt] = __builtin_amdgcn_mfma_f32_16x16x32_bf16(a1, bl, acc[1][nt], 0, 0, 0);
            }
        }
    }
#pragma unroll
    for (int nt = 0; nt < 8; ++nt) {
        int col = nt * 16 + lr;
        float bb = 0.5f * (b1[col] + b2[col]);
#pragma unroll
        for (int mt = 0; mt < 2; ++mt) {
#pragma unroll
            for (int r = 0; r < 4; ++r) {
                int row = m0 + mt * 16 + (lq << 2) + r;
                if (row < M) {
                    float o = fmaxf(0.5f * acc[mt][nt][r] + bb, 0.f);
                    if (C != nullptr) C[(i64)row * H_ + col] = o;
                    if (Cbf != nullptr) Cbf[(i64)row * H_ + col] = f2bf(o);
                }
            }
        }
    }
}

__global__ __launch_bounds__(256) void fuse_kernel(const float* __restrict__ alpha,
                                                   const float* __restrict__ hui,
                                                   const float* __restrict__ hii,
                                                   const float* __restrict__ hia,
                                                   float* __restrict__ fused,
                                                   float* __restrict__ wout) {
    long i = (long)blockIdx.x * 256 + threadIdx.x;
    float a0 = alpha[0], a1 = alpha[1], a2 = alpha[2];
    float mx = fmaxf(a0, fmaxf(a1, a2));
    float e0 = expf(a0 - mx), e1 = expf(a1 - mx), e2 = expf(a2 - mx);
    float inv = 1.f / (e0 + e1 + e2);
    float w0 = e0 * inv, w1 = e1 * inv, w2 = e2 * inv;
    if (i == 0) { wout[0] = w0; wout[1] = w1; wout[2] = w2; }
    long n4 = (long)NI_ * H_ / 4;
    if (i < n4) {
        float4 u = ((const float4*)hui)[i];
        float4 v = ((const float4*)hii)[i];
        float4 t = ((const float4*)hia)[i];
        float4 o;
        o.x = w0 * u.x + w1 * v.x + w2 * t.x;
        o.y = w0 * u.y + w1 * v.y + w2 * t.y;
        o.z = w0 * u.z + w1 * v.z + w2 * t.z;
        o.w = w0 * u.w + w1 * v.w + w2 * t.w;
        ((float4*)fused)[i] = o;
    }
}

extern "C" void kernel_launch(void* const* d_in, const int* in_sizes, int n_in,
                              void* d_out, int out_size, void* d_ws, size_t ws_size,
                              hipStream_t stream) {
    const float* xif  = (const float*)d_in[0];
    const float* uemb = (const float*)d_in[1];
    const float* aemb = (const float*)d_in[2];
    const float* liW  = (const float*)d_in[3];
    const float* lib  = (const float*)d_in[4];
    const float* uiWl = (const float*)d_in[5];
    const float* uibl = (const float*)d_in[6];
    const float* uiWr = (const float*)d_in[7];
    const float* iiWl = (const float*)d_in[8];
    const float* iibl = (const float*)d_in[9];
    const float* iiWr = (const float*)d_in[10];
    const float* iaWl = (const float*)d_in[11];
    const float* iabl = (const float*)d_in[12];
    const float* iaWr = (const float*)d_in[13];
    const float* alpha = (const float*)d_in[14];
    const int* er = (const int*)d_in[15];
    const int* es = (const int*)d_in[16];
    const int* eh = (const int*)d_in[17];

    float* out = (float*)d_out;
    float* FUSED  = out;
    float* OUT_UI = out + (i64)NI_ * H_;
    float* OUT_II = out + (i64)2 * NI_ * H_;
    float* OUT_IA = out + (i64)3 * NI_ * H_;
    float* WOUT   = out + (i64)4 * NI_ * H_;

    // ---- workspace layout: bf16 region first (16B-aligned), then ints ----
    u16* u = (u16*)d_ws;
    i64 uo = 0;
    u16* WTH    = u + uo; uo += 294912;
    u16* WTL    = u + uo; uo += 294912;
    u16* X_bf   = u + uo; uo += (i64)NI_ * H_;
    u16* HI1_bf = u + uo; uo += (i64)NI_ * H_;
    u16* HU1_bf = u + uo; uo += (i64)NU_ * H_;
    u16* HA1_bf = u + uo; uo += (i64)NA_ * H_;
    u16* AGG_bf = u + uo; uo += (i64)NU_ * H_;
    u16* UE_bf  = u + uo; uo += (i64)NU_ * H_;
    u16* AE_bf  = u + uo; uo += (i64)NA_ * H_;

    int* ip = (int*)(u + uo);
    i64 io = 0;
    int* SBT   = ip + io; io += 256;          // SB totals (zeroed, atomic target)
    int* OFF   = ip + io; io += NTOT_ + 4;    // [0]=sentinel; off1 = OFF+1 (inclusive ends)
    int* SBB   = ip + io; io += 256;          // SB bases (immutable)
    int* SBC   = ip + io; io += 256;          // SB cursors (mutate -> ends)
    int* POOL  = ip + io; io += RTOT_;        // final CSR vals
    int* CPOOL = ip + io; io += RTOT_;        // SB-grouped packed records
    int* off1 = OFF + 1;

    // ---- CSR build: histo -> scan -> LDS-binned scatter -> per-SB place ----
    {
        // zero SBT (256 ints) + OFF[0..3] (sentinel): contiguous 260 ints = 65 float4
        fillz_kernel<<<1, 256, 0, stream>>>((float4*)SBT, 65);
        int nblk = (RTOT_ + 4095) / 4096;   // 733
        histo_kernel<<<nblk, 256, 0, stream>>>(er, es, eh, SBT);
        sbscan_kernel<<<1, 256, 0, stream>>>(SBT, SBB, SBC);
        binA_kernel<<<nblk, 256, 0, stream>>>(er, es, eh, SBC, CPOOL);
        binB_kernel<<<NSB_, 256, 0, stream>>>(CPOOL, SBB, SBC, off1, POOL);
    }

    // ---- weight split/transpose ----
    const float* famWl[8] = {uiWl, uiWl, uiWl, iiWl, iiWl, iaWl, iaWl, iaWl};
    const float* famWr[8] = {uiWr, uiWr, uiWr, iiWr, iiWr, iaWr, iaWr, iaWr};
    const float* famBl[8] = {uibl, uibl, uibl, iibl, iibl, iabl, iabl, iabl};
    const int eidx[8] = {0, 1, 4, 0, 2, 0, 1, 5};
    const int sidx[8] = {3, 2, 7, 1, 3, 3, 2, 6};

    WJobs jobs;
    jobs.j[0] = {liW, nullptr, nullptr, 8, 0};
    int base = 32768;
    for (int s = 0; s < 8; ++s) {
        jobs.j[1 + 2 * s] = {famWl[s] + (i64)eidx[s] * 16384, nullptr, nullptr, 7, base};
        base += 16384;
        jobs.j[2 + 2 * s] = {famWr[s] + (i64)eidx[s] * 16384,
                             famWl[s] + (i64)sidx[s] * 16384,
                             famWr[s] + (i64)sidx[s] * 16384, 7, base};
        base += 16384;
    }
    wsplit_kernel<<<(base + 255) / 256, 256, 0, stream>>>(jobs, 17, base, WTH, WTL);

    // ---- bf16 copies of input embedding tables ----
    tobf_kernel<<<((NU_ * H_ / 4) + 255) / 256, 256, 0, stream>>>(
        (const float4*)uemb, (ushort4*)UE_bf, (long)NU_ * H_ / 4);
    tobf_kernel<<<((NA_ * H_ / 4) + 255) / 256, 256, 0, stream>>>(
        (const float4*)aemb, (ushort4*)AE_bf, (long)NA_ * H_ / 4);

    // x_item = xif @ liW + lib  -> bf16 table
    mgemm_x_kernel<<<(NI_ + 127) / 128, 256, 0, stream>>>(xif, WTH, WTL, lib, X_bf, NI_);

    auto gath = [&](const u16* feat, int cbase, int ndst) {
        gatherb_kernel<<<(ndst + 15) / 16, 256, 0, stream>>>(feat, off1 + cbase, POOL, ndst, AGG_bf);
    };
    auto gemm2 = [&](int slot, const u16* A2m, float* Cout, u16* Cbfout, int M) {
        const u16* w1h = WTH + 32768 + (i64)(2 * slot) * 16384;
        const u16* w1l = WTL + 32768 + (i64)(2 * slot) * 16384;
        const u16* w2h = WTH + 32768 + (i64)(2 * slot + 1) * 16384;
        const u16* w2l = WTL + 32768 + (i64)(2 * slot + 1) * 16384;
        const float* be = famBl[slot] + (i64)eidx[slot] * 128;
        const float* bs = famBl[slot] + (i64)sidx[slot] * 128;
        mgemm_d_kernel<<<(M + 127) / 128, 256, 0, stream>>>(
            AGG_bf, w1h, w1l, A2m, w2h, w2l, be, bs, Cout, Cbfout, M);
    };

    // ---- UI branch ----
    gath(UE_bf, B_RI, NI_);
    gemm2(0, X_bf, nullptr, HI1_bf, NI_);
    gath(X_bf, B_RU, NU_);
    gemm2(1, UE_bf, nullptr, HU1_bf, NU_);
    gath(HU1_bf, B_RI, NI_);                 // L1 o_i only (o_u dead)
    gemm2(2, HI1_bf, OUT_UI, nullptr, NI_);

    // ---- II branch ----
    gath(X_bf, B_SI, NI_);
    gemm2(3, X_bf, nullptr, HI1_bf, NI_);
    gath(HI1_bf, B_SI, NI_);
    gemm2(4, HI1_bf, OUT_II, nullptr, NI_);

    // ---- IA branch ----
    gath(X_bf, B_HA, NA_);
    gemm2(5, AE_bf, nullptr, HA1_bf, NA_);
    gath(AE_bf, B_HI, NI_);
    gemm2(6, X_bf, nullptr, HI1_bf, NI_);
    gath(HA1_bf, B_HI, NI_);                 // L1 o_i only (o_a dead)
    gemm2(7, HI1_bf, OUT_IA, nullptr, NI_);

    // ---- fuse ----
    long n4 = (long)NI_ * H_ / 4;
    fuse_kernel<<<(int)((n4 + 255) / 256), 256, 0, stream>>>(
        alpha, OUT_UI, OUT_II, OUT_IA, FUSED, WOUT);
}

// Round 10
// 607.156 us; speedup vs baseline: 2.7578x; 1.0988x over previous
//
#include <hip/hip_runtime.h>

#define NU_ 100000
#define NI_ 50000
#define NA_ 5000
#define FEAT_ 256
#define H_ 128
#define ER_ 1000000
#define ES_ 500000
#define EH_ 250000

#define NTOT_ (3 * NI_ + NU_ + NA_)      // 255000 combined nodes
#define RTOT_ (2 * ER_ + ES_ + 2 * EH_)  // 3,000,000 records
#define NSB_ ((NTOT_ + 1023) / 1024)     // 250 super-buckets (1024 nodes each)
// node-space bases (order defines pool layout)
#define B_RI 0
#define B_RU (NI_)
#define B_SI (NI_ + NU_)
#define B_HA (2 * NI_ + NU_)
#define B_HI (2 * NI_ + NU_ + NA_)

typedef long long i64;
typedef unsigned short u16;
typedef unsigned int u32;
typedef __attribute__((ext_vector_type(8))) short bf16x8;
typedef __attribute__((ext_vector_type(4))) float f32x4;

__device__ __forceinline__ u16 f2bf(float v) {           // round-to-nearest-even
    u32 b = __float_as_uint(v);
    b += 0x7fff + ((b >> 16) & 1);
    return (u16)(b >> 16);
}
__device__ __forceinline__ float bf2f(u16 v) {
    return __uint_as_float((u32)v << 16);
}

__global__ __launch_bounds__(256) void fillz_kernel(float4* __restrict__ p, long n4) {
    long i = (long)blockIdx.x * 256 + threadIdx.x;
    if (i < n4) p[i] = make_float4(0.f, 0.f, 0.f, 0.f);
}

// fp32 -> bf16 table convert
__global__ __launch_bounds__(256) void tobf_kernel(const float4* __restrict__ in,
                                                   ushort4* __restrict__ out, long n4) {
    long i = (long)blockIdx.x * 256 + threadIdx.x;
    if (i >= n4) return;
    float4 v = in[i];
    ushort4 o;
    o.x = f2bf(v.x); o.y = f2bf(v.y); o.z = f2bf(v.z); o.w = f2bf(v.w);
    out[i] = o;
}

// record r -> (node, val). val < 2^17 (ids < 100000), node < 255000.
__device__ __forceinline__ void rec_of(int r, const int* __restrict__ er,
                                       const int* __restrict__ es,
                                       const int* __restrict__ eh,
                                       int& node, int& val) {
    if (r < 2 * ER_) {
        int e = r >> 1;
        if ((r & 1) == 0) { node = B_RI + er[ER_ + e]; val = er[e]; }
        else              { node = B_RU + er[e];       val = er[ER_ + e]; }
    } else if (r < 2 * ER_ + ES_) {
        int e = r - 2 * ER_;
        node = B_SI + es[ES_ + e]; val = es[e];
    } else {
        int q = r - 2 * ER_ - ES_;
        int e = q >> 1;
        if ((q & 1) == 0) { node = B_HA + eh[EH_ + e]; val = eh[e]; }
        else              { node = B_HI + eh[e];       val = eh[EH_ + e]; }
    }
}

// ---- pass 1: per-block LDS histogram over super-buckets, global add ----
__global__ __launch_bounds__(256) void histo_kernel(const int* __restrict__ er,
                                                    const int* __restrict__ es,
                                                    const int* __restrict__ eh,
                                                    int* __restrict__ sbt) {
    __shared__ int h[256];
    int t = threadIdx.x;
    h[t] = 0;
    __syncthreads();
    int base = blockIdx.x * 4096;
#pragma unroll
    for (int i = 0; i < 16; ++i) {
        int r = base + i * 256 + t;
        if (r < RTOT_) {
            int node, val;
            rec_of(r, er, es, eh, node, val);
            atomicAdd(&h[node >> 10], 1);
        }
    }
    __syncthreads();
    if (t < NSB_ && h[t] > 0) atomicAdd(&sbt[t], h[t]);
}

// ---- pass 2: one block scans the 250 SB totals -> SBB (bases) + SBC (cursors) ----
__global__ __launch_bounds__(256) void sbscan_kernel(const int* __restrict__ sbt,
                                                     int* __restrict__ sbb,
                                                     int* __restrict__ sbc) {
    int t = threadIdx.x;
    int v = (t < NSB_) ? sbt[t] : 0;
    int incl = v;
    int lane = t & 63;
#pragma unroll
    for (int d = 1; d < 64; d <<= 1) {
        int u = __shfl_up(incl, d);
        if (lane >= d) incl += u;
    }
    __shared__ int wsum[4];
    if (lane == 63) wsum[t >> 6] = incl;
    __syncthreads();
    int wo = 0;
    for (int i = 0; i < (t >> 6); ++i) wo += wsum[i];
    int ex = wo + incl - v;
    if (t < NSB_) { sbb[t] = ex; sbc[t] = ex; }
}

// ---- pass 3: LDS-binned scatter. One global atomic per (block, SB); records
// written as contiguous runs into the SB's region of cpool (coalesced). ----
__global__ __launch_bounds__(256) void binA_kernel(const int* __restrict__ er,
                                                   const int* __restrict__ es,
                                                   const int* __restrict__ eh,
                                                   int* __restrict__ sbc,
                                                   int* __restrict__ cpool) {
    __shared__ int h[256];
    __shared__ int gof[256];
    int t = threadIdx.x;
    h[t] = 0;
    __syncthreads();
    int base = blockIdx.x * 4096;
    int sbs[16];
    u32 recs[16];
#pragma unroll
    for (int i = 0; i < 16; ++i) {
        int r = base + i * 256 + t;
        sbs[i] = -1;
        if (r < RTOT_) {
            int node, val;
            rec_of(r, er, es, eh, node, val);
            int sb = node >> 10;
            sbs[i] = sb;
            recs[i] = ((u32)(node & 1023) << 17) | (u32)val;
            atomicAdd(&h[sb], 1);
        }
    }
    __syncthreads();
    if (t < 256) {
        int c = h[t];
        if (c > 0) gof[t] = atomicAdd(&sbc[t], c);
        h[t] = 0;   // reuse as block-local cursor
    }
    __syncthreads();
#pragma unroll
    for (int i = 0; i < 16; ++i) {
        if (sbs[i] >= 0) {
            int slot = atomicAdd(&h[sbs[i]], 1);
            cpool[gof[sbs[i]] + slot] = (int)recs[i];
        }
    }
}

// ---- pass 4: one 1024-thread block per SB (16 waves for latency hiding).
// Dense span [SBB[sb], SBC[sb]) of cpool. LDS node histogram -> 16-wave scan
// -> write off1 (inclusive ends) -> place vals via LDS cursors. ----
__global__ __launch_bounds__(1024) void binB_kernel(const int* __restrict__ cpool,
                                                    const int* __restrict__ sbb,
                                                    const int* __restrict__ sbc,
                                                    int* __restrict__ off1,
                                                    int* __restrict__ pool) {
    __shared__ int c[1024];
    __shared__ int b[1024];
    __shared__ int wsum[16];
    int sb = blockIdx.x, t = threadIdx.x;
    int start = sbb[sb], end = sbc[sb];
    c[t] = 0;
    __syncthreads();
    for (int j = start + t; j < end; j += 1024)
        atomicAdd(&c[((u32)cpool[j]) >> 17], 1);
    __syncthreads();
    int v = c[t];
    int incl = v;
    int lane = t & 63;
#pragma unroll
    for (int d = 1; d < 64; d <<= 1) {
        int u = __shfl_up(incl, d);
        if (lane >= d) incl += u;
    }
    if (lane == 63) wsum[t >> 6] = incl;
    __syncthreads();
    int wo = 0;
    for (int i = 0; i < (t >> 6); ++i) wo += wsum[i];
    int ex = wo + incl - v;            // exclusive prefix within SB
    int node = sb * 1024 + t;
    if (node < NTOT_) off1[node] = start + ex + v;   // inclusive end
    b[t] = start + ex;                               // cursor
    __syncthreads();
    for (int j = start + t; j < end; j += 1024) {
        u32 rec = (u32)cpool[j];
        int pos = atomicAdd(&b[rec >> 17], 1);
        pool[pos] = (int)(rec & 0x1FFFF);
    }
}

#define ACC8(A, V)                                                            \
    {                                                                         \
        A[0] += bf2f((u16)(V.x & 0xffff)); A[1] += bf2f((u16)(V.x >> 16));    \
        A[2] += bf2f((u16)(V.y & 0xffff)); A[3] += bf2f((u16)(V.y >> 16));    \
        A[4] += bf2f((u16)(V.z & 0xffff)); A[5] += bf2f((u16)(V.z >> 16));    \
        A[6] += bf2f((u16)(V.w & 0xffff)); A[7] += bf2f((u16)(V.w >> 16));    \
    }

// gather-mean over bf16 features: 16 lanes per dst row, 16B (8 cols) per lane.
// off1 holds inclusive ends; off1[row-1] (sentinel-safe) is the start.
__global__ __launch_bounds__(256) void gatherb_kernel(const u16* __restrict__ feat,
                                                      const int* __restrict__ off1,
                                                      const int* __restrict__ pool,
                                                      int n,
                                                      u16* __restrict__ agg) {
    int row = blockIdx.x * 16 + (threadIdx.x >> 4);
    if (row >= n) return;
    int lane = (threadIdx.x & 15) * 8;
    int start = off1[row - 1];
    int end = off1[row];
    float a0[8], a1[8], a2[8], a3[8];
#pragma unroll
    for (int k = 0; k < 8; ++k) { a0[k] = 0.f; a1[k] = 0.f; a2[k] = 0.f; a3[k] = 0.f; }
    int j = start;
    for (; j + 4 <= end; j += 4) {
        int s0 = pool[j], s1 = pool[j + 1], s2 = pool[j + 2], s3 = pool[j + 3];
        uint4 v0 = *(const uint4*)&feat[(i64)s0 * H_ + lane];
        uint4 v1 = *(const uint4*)&feat[(i64)s1 * H_ + lane];
        uint4 v2 = *(const uint4*)&feat[(i64)s2 * H_ + lane];
        uint4 v3 = *(const uint4*)&feat[(i64)s3 * H_ + lane];
        ACC8(a0, v0); ACC8(a1, v1); ACC8(a2, v2); ACC8(a3, v3);
    }
    for (; j < end; ++j) {
        int s0 = pool[j];
        uint4 v0 = *(const uint4*)&feat[(i64)s0 * H_ + lane];
        ACC8(a0, v0);
    }
    float inv = 1.0f / fmaxf((float)(end - start), 1.0f);
    uint4 o;
    float r0, r1;
    r0 = (a0[0] + a1[0] + a2[0] + a3[0]) * inv; r1 = (a0[1] + a1[1] + a2[1] + a3[1]) * inv;
    o.x = (u32)f2bf(r0) | ((u32)f2bf(r1) << 16);
    r0 = (a0[2] + a1[2] + a2[2] + a3[2]) * inv; r1 = (a0[3] + a1[3] + a2[3] + a3[3]) * inv;
    o.y = (u32)f2bf(r0) | ((u32)f2bf(r1) << 16);
    r0 = (a0[4] + a1[4] + a2[4] + a3[4]) * inv; r1 = (a0[5] + a1[5] + a2[5] + a3[5]) * inv;
    o.z = (u32)f2bf(r0) | ((u32)f2bf(r1) << 16);
    r0 = (a0[6] + a1[6] + a2[6] + a3[6]) * inv; r1 = (a0[7] + a1[7] + a2[7] + a3[7]) * inv;
    o.w = (u32)f2bf(r0) | ((u32)f2bf(r1) << 16);
    *(uint4*)&agg[(i64)row * H_ + lane] = o;
}

// ---- weight prep: W (fp32 [K][128], optionally sum of 3) -> frag-tiled hi/lo bf16 ----
// frag layout: index = ((kc*8 + nt)*64 + l)*8 + e  holds  W_T[n=nt*16+(l&15)][k=kc*32+((l>>4)<<3)+e]
struct WJob {
    const float* s0; const float* s1; const float* s2;
    int logK; int base;
};
struct WJobs { WJob j[17]; };

__global__ __launch_bounds__(256) void wsplit_kernel(WJobs jobs, int njobs, int total,
                                                     u16* __restrict__ WTH,
                                                     u16* __restrict__ WTL) {
    int gid = blockIdx.x * 256 + threadIdx.x;
    if (gid >= total) return;
    int ji = 0;
    for (int i = 1; i < 17; ++i)
        if (i < njobs && gid >= jobs.j[i].base) ji = i;
    WJob jb = jobs.j[ji];
    int local = gid - jb.base;
    int e = local & 7;
    int l = (local >> 3) & 63;
    int nt = (local >> 9) & 7;
    int kc = local >> 12;
    int n = nt * 16 + (l & 15);
    int k = kc * 32 + ((l >> 4) << 3) + e;
    i64 si = (i64)k * 128 + n;
    float v = jb.s0[si];
    if (jb.s1 != nullptr) v += jb.s1[si] + jb.s2[si];
    u32 b = __float_as_uint(v);
    u16 h = (u16)(b >> 16);                       // truncation split: v = hi + lo
    float rem = v - __uint_as_float(b & 0xffff0000u);
    WTH[gid] = h;
    WTL[gid] = (u16)(__float_as_uint(rem) >> 16);
}

// ---- x_item GEMM: fp32 A (xif, K=256), 3-term hi/lo split, bf16 output only ----
__device__ __forceinline__ void split8(const float* f, bf16x8& h, bf16x8& lo) {
#pragma unroll
    for (int i = 0; i < 8; ++i) {
        u32 b = __float_as_uint(f[i]);
        h[i] = (short)(u16)(b >> 16);
        float rem = f[i] - __uint_as_float(b & 0xffff0000u);
        lo[i] = (short)(u16)(__float_as_uint(rem) >> 16);
    }
}

__global__ __launch_bounds__(256) void mgemm_x_kernel(
    const float* __restrict__ A, const u16* __restrict__ Wh, const u16* __restrict__ Wl,
    const float* __restrict__ bias, u16* __restrict__ Cbf, int M) {
    int t = threadIdx.x;
    int w = t >> 6, l = t & 63;
    int lr = l & 15, lq = l >> 4;
    int m0 = blockIdx.x * 128 + w * 32;

    f32x4 acc[2][8];
#pragma unroll
    for (int mt = 0; mt < 2; ++mt)
#pragma unroll
        for (int nt = 0; nt < 8; ++nt) acc[mt][nt] = (f32x4){0.f, 0.f, 0.f, 0.f};

    for (int kc = 0; kc < 8; ++kc) {   // K = 256
        bf16x8 ah0, al0, ah1, al1;
        {
            int row = m0 + lr;
            float f[8];
            if (row < M) {
                const float* ap = &A[(i64)row * FEAT_ + kc * 32 + lq * 8];
                *(float4*)&f[0] = *(const float4*)ap;
                *(float4*)&f[4] = *(const float4*)(ap + 4);
            } else {
#pragma unroll
                for (int i = 0; i < 8; ++i) f[i] = 0.f;
            }
            split8(f, ah0, al0);
        }
        {
            int row = m0 + 16 + lr;
            float f[8];
            if (row < M) {
                const float* ap = &A[(i64)row * FEAT_ + kc * 32 + lq * 8];
                *(float4*)&f[0] = *(const float4*)ap;
                *(float4*)&f[4] = *(const float4*)(ap + 4);
            } else {
#pragma unroll
                for (int i = 0; i < 8; ++i) f[i] = 0.f;
            }
            split8(f, ah1, al1);
        }
        const u16* whp = Wh + ((i64)kc * 8) * 512 + (i64)l * 8;
        const u16* wlp = Wl + ((i64)kc * 8) * 512 + (i64)l * 8;
#pragma unroll
        for (int nt = 0; nt < 8; ++nt) {
            bf16x8 bh = *(const bf16x8*)(whp + nt * 512);
            bf16x8 bl = *(const bf16x8*)(wlp + nt * 512);
            acc[0][nt] = __builtin_amdgcn_mfma_f32_16x16x32_bf16(ah0, bh, acc[0][nt], 0, 0, 0);
            acc[1][nt] = __builtin_amdgcn_mfma_f32_16x16x32_bf16(ah1, bh, acc[1][nt], 0, 0, 0);
            acc[0][nt] = __builtin_amdgcn_mfma_f32_16x16x32_bf16(al0, bh, acc[0][nt], 0, 0, 0);
            acc[1][nt] = __builtin_amdgcn_mfma_f32_16x16x32_bf16(al1, bh, acc[1][nt], 0, 0, 0);
            acc[0][nt] = __builtin_amdgcn_mfma_f32_16x16x32_bf16(ah0, bl, acc[0][nt], 0, 0, 0);
            acc[1][nt] = __builtin_amdgcn_mfma_f32_16x16x32_bf16(ah1, bl, acc[1][nt], 0, 0, 0);
        }
    }
#pragma unroll
    for (int nt = 0; nt < 8; ++nt) {
        int col = nt * 16 + lr;
        float bb = bias[col];
#pragma unroll
        for (int mt = 0; mt < 2; ++mt) {
#pragma unroll
            for (int r = 0; r < 4; ++r) {
                int row = m0 + mt * 16 + (lq << 2) + r;
                if (row < M) Cbf[(i64)row * H_ + col] = f2bf(acc[mt][nt][r] + bb);
            }
        }
    }
}

// ---- dual GEMM, bf16 A operands (K=128 each), 2-term W split ----
__global__ __launch_bounds__(256) void mgemm_d_kernel(
    const u16* __restrict__ A1, const u16* __restrict__ W1h, const u16* __restrict__ W1l,
    const u16* __restrict__ A2, const u16* __restrict__ W2h, const u16* __restrict__ W2l,
    const float* __restrict__ b1, const float* __restrict__ b2,
    float* __restrict__ C, u16* __restrict__ Cbf, int M) {
    int t = threadIdx.x;
    int w = t >> 6, l = t & 63;
    int lr = l & 15, lq = l >> 4;
    int m0 = blockIdx.x * 128 + w * 32;

    f32x4 acc[2][8];
#pragma unroll
    for (int mt = 0; mt < 2; ++mt)
#pragma unroll
        for (int nt = 0; nt < 8; ++nt) acc[mt][nt] = (f32x4){0.f, 0.f, 0.f, 0.f};

#pragma unroll
    for (int mat = 0; mat < 2; ++mat) {
        const u16* A = mat ? A2 : A1;
        const u16* Wh = mat ? W2h : W1h;
        const u16* Wl = mat ? W2l : W1l;
#pragma unroll
        for (int kc = 0; kc < 4; ++kc) {   // K = 128
            bf16x8 a0 = {0, 0, 0, 0, 0, 0, 0, 0}, a1 = {0, 0, 0, 0, 0, 0, 0, 0};
            int row0 = m0 + lr, row1 = m0 + 16 + lr;
            if (row0 < M) a0 = *(const bf16x8*)&A[(i64)row0 * H_ + kc * 32 + lq * 8];
            if (row1 < M) a1 = *(const bf16x8*)&A[(i64)row1 * H_ + kc * 32 + lq * 8];
            const u16* whp = Wh + ((i64)kc * 8) * 512 + (i64)l * 8;
            const u16* wlp = Wl + ((i64)kc * 8) * 512 + (i64)l * 8;
#pragma unroll
            for (int nt = 0; nt < 8; ++nt) {
                bf16x8 bh = *(const bf16x8*)(whp + nt * 512);
                bf16x8 bl = *(const bf16x8*)(wlp + nt * 512);
                acc[0][nt] = __builtin_amdgcn_mfma_f32_16x16x32_bf16(a0, bh, acc[0][nt], 0, 0, 0);
                acc[1][nt] = __builtin_amdgcn_mfma_f32_16x16x32_bf16(a1, bh, acc[1][nt], 0, 0, 0);
                acc[0][nt] = __builtin_amdgcn_mfma_f32_16x16x32_bf16(a0, bl, acc[0][nt], 0, 0, 0);
                acc[1][nt] = __builtin_amdgcn_mfma_f32_16x16x32_bf16(a1, bl, acc[1][nt], 0, 0, 0);
            }
        }
    }
#pragma unroll
    for (int nt = 0; nt < 8; ++nt) {
        int col = nt * 16 + lr;
        float bb = 0.5f * (b1[col] + b2[col]);
#pragma unroll
        for (int mt = 0; mt < 2; ++mt) {
#pragma unroll
            for (int r = 0; r < 4; ++r) {
                int row = m0 + mt * 16 + (lq << 2) + r;
                if (row < M) {
                    float o = fmaxf(0.5f * acc[mt][nt][r] + bb, 0.f);
                    if (C != nullptr) C[(i64)row * H_ + col] = o;
                    if (Cbf != nullptr) Cbf[(i64)row * H_ + col] = f2bf(o);
                }
            }
        }
    }
}

__global__ __launch_bounds__(256) void fuse_kernel(const float* __restrict__ alpha,
                                                   const float* __restrict__ hui,
                                                   const float* __restrict__ hii,
                                                   const float* __restrict__ hia,
                                                   float* __restrict__ fused,
                                                   float* __restrict__ wout) {
    long i = (long)blockIdx.x * 256 + threadIdx.x;
    float a0 = alpha[0], a1 = alpha[1], a2 = alpha[2];
    float mx = fmaxf(a0, fmaxf(a1, a2));
    float e0 = expf(a0 - mx), e1 = expf(a1 - mx), e2 = expf(a2 - mx);
    float inv = 1.f / (e0 + e1 + e2);
    float w0 = e0 * inv, w1 = e1 * inv, w2 = e2 * inv;
    if (i == 0) { wout[0] = w0; wout[1] = w1; wout[2] = w2; }
    long n4 = (long)NI_ * H_ / 4;
    if (i < n4) {
        float4 u = ((const float4*)hui)[i];
        float4 v = ((const float4*)hii)[i];
        float4 t = ((const float4*)hia)[i];
        float4 o;
        o.x = w0 * u.x + w1 * v.x + w2 * t.x;
        o.y = w0 * u.y + w1 * v.y + w2 * t.y;
        o.z = w0 * u.z + w1 * v.z + w2 * t.z;
        o.w = w0 * u.w + w1 * v.w + w2 * t.w;
        ((float4*)fused)[i] = o;
    }
}

extern "C" void kernel_launch(void* const* d_in, const int* in_sizes, int n_in,
                              void* d_out, int out_size, void* d_ws, size_t ws_size,
                              hipStream_t stream) {
    const float* xif  = (const float*)d_in[0];
    const float* uemb = (const float*)d_in[1];
    const float* aemb = (const float*)d_in[2];
    const float* liW  = (const float*)d_in[3];
    const float* lib  = (const float*)d_in[4];
    const float* uiWl = (const float*)d_in[5];
    const float* uibl = (const float*)d_in[6];
    const float* uiWr = (const float*)d_in[7];
    const float* iiWl = (const float*)d_in[8];
    const float* iibl = (const float*)d_in[9];
    const float* iiWr = (const float*)d_in[10];
    const float* iaWl = (const float*)d_in[11];
    const float* iabl = (const float*)d_in[12];
    const float* iaWr = (const float*)d_in[13];
    const float* alpha = (const float*)d_in[14];
    const int* er = (const int*)d_in[15];
    const int* es = (const int*)d_in[16];
    const int* eh = (const int*)d_in[17];

    float* out = (float*)d_out;
    float* FUSED  = out;
    float* OUT_UI = out + (i64)NI_ * H_;
    float* OUT_II = out + (i64)2 * NI_ * H_;
    float* OUT_IA = out + (i64)3 * NI_ * H_;
    float* WOUT   = out + (i64)4 * NI_ * H_;

    // ---- workspace layout: bf16 region first (16B-aligned), then ints ----
    u16* u = (u16*)d_ws;
    i64 uo = 0;
    u16* WTH    = u + uo; uo += 294912;
    u16* WTL    = u + uo; uo += 294912;
    u16* X_bf   = u + uo; uo += (i64)NI_ * H_;
    u16* HI1_bf = u + uo; uo += (i64)NI_ * H_;
    u16* HU1_bf = u + uo; uo += (i64)NU_ * H_;
    u16* HA1_bf = u + uo; uo += (i64)NA_ * H_;
    u16* AGG_bf = u + uo; uo += (i64)NU_ * H_;
    u16* UE_bf  = u + uo; uo += (i64)NU_ * H_;
    u16* AE_bf  = u + uo; uo += (i64)NA_ * H_;

    int* ip = (int*)(u + uo);
    i64 io = 0;
    int* SBT   = ip + io; io += 256;          // SB totals (zeroed, atomic target)
    int* OFF   = ip + io; io += NTOT_ + 4;    // [0]=sentinel; off1 = OFF+1 (inclusive ends)
    int* SBB   = ip + io; io += 256;          // SB bases (immutable)
    int* SBC   = ip + io; io += 256;          // SB cursors (mutate -> ends)
    int* POOL  = ip + io; io += RTOT_;        // final CSR vals
    int* CPOOL = ip + io; io += RTOT_;        // SB-grouped packed records
    int* off1 = OFF + 1;

    // ---- CSR build: histo -> scan -> LDS-binned scatter -> per-SB place ----
    {
        // zero SBT (256 ints) + OFF[0..3] (sentinel): contiguous 260 ints = 65 float4
        fillz_kernel<<<1, 256, 0, stream>>>((float4*)SBT, 65);
        int nblk = (RTOT_ + 4095) / 4096;   // 733
        histo_kernel<<<nblk, 256, 0, stream>>>(er, es, eh, SBT);
        sbscan_kernel<<<1, 256, 0, stream>>>(SBT, SBB, SBC);
        binA_kernel<<<nblk, 256, 0, stream>>>(er, es, eh, SBC, CPOOL);
        binB_kernel<<<NSB_, 1024, 0, stream>>>(CPOOL, SBB, SBC, off1, POOL);
    }

    // ---- weight split/transpose ----
    const float* famWl[8] = {uiWl, uiWl, uiWl, iiWl, iiWl, iaWl, iaWl, iaWl};
    const float* famWr[8] = {uiWr, uiWr, uiWr, iiWr, iiWr, iaWr, iaWr, iaWr};
    const float* famBl[8] = {uibl, uibl, uibl, iibl, iibl, iabl, iabl, iabl};
    const int eidx[8] = {0, 1, 4, 0, 2, 0, 1, 5};
    const int sidx[8] = {3, 2, 7, 1, 3, 3, 2, 6};

    WJobs jobs;
    jobs.j[0] = {liW, nullptr, nullptr, 8, 0};
    int base = 32768;
    for (int s = 0; s < 8; ++s) {
        jobs.j[1 + 2 * s] = {famWl[s] + (i64)eidx[s] * 16384, nullptr, nullptr, 7, base};
        base += 16384;
        jobs.j[2 + 2 * s] = {famWr[s] + (i64)eidx[s] * 16384,
                             famWl[s] + (i64)sidx[s] * 16384,
                             famWr[s] + (i64)sidx[s] * 16384, 7, base};
        base += 16384;
    }
    wsplit_kernel<<<(base + 255) / 256, 256, 0, stream>>>(jobs, 17, base, WTH, WTL);

    // ---- bf16 copies of input embedding tables ----
    tobf_kernel<<<((NU_ * H_ / 4) + 255) / 256, 256, 0, stream>>>(
        (const float4*)uemb, (ushort4*)UE_bf, (long)NU_ * H_ / 4);
    tobf_kernel<<<((NA_ * H_ / 4) + 255) / 256, 256, 0, stream>>>(
        (const float4*)aemb, (ushort4*)AE_bf, (long)NA_ * H_ / 4);

    // x_item = xif @ liW + lib  -> bf16 table
    mgemm_x_kernel<<<(NI_ + 127) / 128, 256, 0, stream>>>(xif, WTH, WTL, lib, X_bf, NI_);

    auto gath = [&](const u16* feat, int cbase, int ndst) {
        gatherb_kernel<<<(ndst + 15) / 16, 256, 0, stream>>>(feat, off1 + cbase, POOL, ndst, AGG_bf);
    };
    auto gemm2 = [&](int slot, const u16* A2m, float* Cout, u16* Cbfout, int M) {
        const u16* w1h = WTH + 32768 + (i64)(2 * slot) * 16384;
        const u16* w1l = WTL + 32768 + (i64)(2 * slot) * 16384;
        const u16* w2h = WTH + 32768 + (i64)(2 * slot + 1) * 16384;
        const u16* w2l = WTL + 32768 + (i64)(2 * slot + 1) * 16384;
        const float* be = famBl[slot] + (i64)eidx[slot] * 128;
        const float* bs = famBl[slot] + (i64)sidx[slot] * 128;
        mgemm_d_kernel<<<(M + 127) / 128, 256, 0, stream>>>(
            AGG_bf, w1h, w1l, A2m, w2h, w2l, be, bs, Cout, Cbfout, M);
    };

    // ---- UI branch ----
    gath(UE_bf, B_RI, NI_);
    gemm2(0, X_bf, nullptr, HI1_bf, NI_);
    gath(X_bf, B_RU, NU_);
    gemm2(1, UE_bf, nullptr, HU1_bf, NU_);
    gath(HU1_bf, B_RI, NI_);                 // L1 o_i only (o_u dead)
    gemm2(2, HI1_bf, OUT_UI, nullptr, NI_);

    // ---- II branch ----
    gath(X_bf, B_SI, NI_);
    gemm2(3, X_bf, nullptr, HI1_bf, NI_);
    gath(HI1_bf, B_SI, NI_);
    gemm2(4, HI1_bf, OUT_II, nullptr, NI_);

    // ---- IA branch ----
    gath(X_bf, B_HA, NA_);
    gemm2(5, AE_bf, nullptr, HA1_bf, NA_);
    gath(AE_bf, B_HI, NI_);
    gemm2(6, X_bf, nullptr, HI1_bf, NI_);
    gath(HA1_bf, B_HI, NI_);                 // L1 o_i only (o_a dead)
    gemm2(7, HI1_bf, OUT_IA, nullptr, NI_);

    // ---- fuse ----
    long n4 = (long)NI_ * H_ / 4;
    fuse_kernel<<<(int)((n4 + 255) / 256), 256, 0, stream>>>(
        alpha, OUT_UI, OUT_II, OUT_IA, FUSED, WOUT);
}

// Round 11
// 549.697 us; speedup vs baseline: 3.0461x; 1.1045x over previous
//
#include <hip/hip_runtime.h>

#define NU_ 100000
#define NI_ 50000
#define NA_ 5000
#define FEAT_ 256
#define H_ 128
#define ER_ 1000000
#define ES_ 500000
#define EH_ 250000

#define NTOT_ (3 * NI_ + NU_ + NA_)      // 255000 combined nodes
#define RTOT_ (2 * ER_ + ES_ + 2 * EH_)  // 3,000,000 records
#define NSB_ ((NTOT_ + 1023) / 1024)     // 250 super-buckets (1024 nodes each)
#define SBCAP_ 65536                     // CPOOL region per SB (max load ~52K)
// node-space bases (order defines pool layout)
#define B_RI 0
#define B_RU (NI_)
#define B_SI (NI_ + NU_)
#define B_HA (2 * NI_ + NU_)
#define B_HI (2 * NI_ + NU_ + NA_)

typedef long long i64;
typedef unsigned short u16;
typedef unsigned int u32;
typedef __attribute__((ext_vector_type(8))) short bf16x8;
typedef __attribute__((ext_vector_type(4))) float f32x4;

__device__ __forceinline__ u16 f2bf(float v) {           // round-to-nearest-even
    u32 b = __float_as_uint(v);
    b += 0x7fff + ((b >> 16) & 1);
    return (u16)(b >> 16);
}
__device__ __forceinline__ float bf2f(u16 v) {
    return __uint_as_float((u32)v << 16);
}

// fp32 -> bf16 table convert
__global__ __launch_bounds__(256) void tobf_kernel(const float4* __restrict__ in,
                                                   ushort4* __restrict__ out, long n4) {
    long i = (long)blockIdx.x * 256 + threadIdx.x;
    if (i >= n4) return;
    float4 v = in[i];
    ushort4 o;
    o.x = f2bf(v.x); o.y = f2bf(v.y); o.z = f2bf(v.z); o.w = f2bf(v.w);
    out[i] = o;
}

// record r -> (node, val). val < 2^17 (ids < 100000), node < 255000.
__device__ __forceinline__ void rec_of(int r, const int* __restrict__ er,
                                       const int* __restrict__ es,
                                       const int* __restrict__ eh,
                                       int& node, int& val) {
    if (r < 2 * ER_) {
        int e = r >> 1;
        if ((r & 1) == 0) { node = B_RI + er[ER_ + e]; val = er[e]; }
        else              { node = B_RU + er[e];       val = er[ER_ + e]; }
    } else if (r < 2 * ER_ + ES_) {
        int e = r - 2 * ER_;
        node = B_SI + es[ES_ + e]; val = es[e];
    } else {
        int q = r - 2 * ER_ - ES_;
        int e = q >> 1;
        if ((q & 1) == 0) { node = B_HA + eh[EH_ + e]; val = eh[e]; }
        else              { node = B_HI + eh[e];       val = eh[EH_ + e]; }
    }
}

// init SB cursors to fixed strided bases; zero the off1 sentinel
__global__ __launch_bounds__(256) void sbinit_kernel(int* __restrict__ sbc,
                                                     int* __restrict__ OFF) {
    int t = threadIdx.x;
    sbc[t] = t << 16;          // region base = sb * SBCAP_
    if (t < 4) OFF[t] = 0;     // sentinel (off1[-1] = 0)
}

// ---- pass 1: LDS-binned scatter. One global atomic per (block, SB); records
// written as contiguous runs into the SB's fixed region of cpool (coalesced). ----
__global__ __launch_bounds__(256) void binA_kernel(const int* __restrict__ er,
                                                   const int* __restrict__ es,
                                                   const int* __restrict__ eh,
                                                   int* __restrict__ sbc,
                                                   int* __restrict__ cpool) {
    __shared__ int h[256];
    __shared__ int gof[256];
    int t = threadIdx.x;
    h[t] = 0;
    __syncthreads();
    int base = blockIdx.x * 4096;
    int sbs[16];
    u32 recs[16];
#pragma unroll
    for (int i = 0; i < 16; ++i) {
        int r = base + i * 256 + t;
        sbs[i] = -1;
        if (r < RTOT_) {
            int node, val;
            rec_of(r, er, es, eh, node, val);
            int sb = node >> 10;
            sbs[i] = sb;
            recs[i] = ((u32)(node & 1023) << 17) | (u32)val;
            atomicAdd(&h[sb], 1);
        }
    }
    __syncthreads();
    {
        int c = h[t];
        if (c > 0) gof[t] = atomicAdd(&sbc[t], c);
        h[t] = 0;   // reuse as block-local cursor
    }
    __syncthreads();
#pragma unroll
    for (int i = 0; i < 16; ++i) {
        if (sbs[i] >= 0) {
            int slot = atomicAdd(&h[sbs[i]], 1);
            cpool[gof[sbs[i]] + slot] = (int)recs[i];
        }
    }
}

// ---- pass 2: one block: per-SB counts (sbc - base) -> exclusive scan -> SBB
// (dense global bases for the final POOL layout) ----
__global__ __launch_bounds__(256) void sbscan_kernel(const int* __restrict__ sbc,
                                                     int* __restrict__ sbb) {
    int t = threadIdx.x;
    int v = (t < NSB_) ? (sbc[t] - (t << 16)) : 0;
    int incl = v;
    int lane = t & 63;
#pragma unroll
    for (int d = 1; d < 64; d <<= 1) {
        int u = __shfl_up(incl, d);
        if (lane >= d) incl += u;
    }
    __shared__ int wsum[4];
    if (lane == 63) wsum[t >> 6] = incl;
    __syncthreads();
    int wo = 0;
    for (int i = 0; i < (t >> 6); ++i) wo += wsum[i];
    if (t < NSB_) sbb[t] = wo + incl - v;
}

// ---- pass 3: one 1024-thread block per SB (16 waves). Rec span
// [sb<<16, sbc[sb]) of cpool; dense base SBB[sb]. LDS node histogram ->
// 16-wave scan -> write off1 (inclusive ends) -> place vals via LDS cursors. ----
__global__ __launch_bounds__(1024) void binB_kernel(const int* __restrict__ cpool,
                                                    const int* __restrict__ sbb,
                                                    const int* __restrict__ sbc,
                                                    int* __restrict__ off1,
                                                    int* __restrict__ pool) {
    __shared__ int c[1024];
    __shared__ int b[1024];
    __shared__ int wsum[16];
    int sb = blockIdx.x, t = threadIdx.x;
    int rlo = sb << 16, rhi = sbc[sb];
    int base = sbb[sb];
    c[t] = 0;
    __syncthreads();
    for (int j = rlo + t; j < rhi; j += 1024)
        atomicAdd(&c[((u32)cpool[j]) >> 17], 1);
    __syncthreads();
    int v = c[t];
    int incl = v;
    int lane = t & 63;
#pragma unroll
    for (int d = 1; d < 64; d <<= 1) {
        int u = __shfl_up(incl, d);
        if (lane >= d) incl += u;
    }
    if (lane == 63) wsum[t >> 6] = incl;
    __syncthreads();
    int wo = 0;
    for (int i = 0; i < (t >> 6); ++i) wo += wsum[i];
    int ex = wo + incl - v;            // exclusive prefix within SB
    int node = sb * 1024 + t;
    if (node < NTOT_) off1[node] = base + ex + v;   // inclusive end
    b[t] = base + ex;                               // cursor
    __syncthreads();
    for (int j = rlo + t; j < rhi; j += 1024) {
        u32 rec = (u32)cpool[j];
        int pos = atomicAdd(&b[rec >> 17], 1);
        pool[pos] = (int)(rec & 0x1FFFF);
    }
}

#define ACC8(A, V)                                                            \
    {                                                                         \
        A[0] += bf2f((u16)(V.x & 0xffff)); A[1] += bf2f((u16)(V.x >> 16));    \
        A[2] += bf2f((u16)(V.y & 0xffff)); A[3] += bf2f((u16)(V.y >> 16));    \
        A[4] += bf2f((u16)(V.z & 0xffff)); A[5] += bf2f((u16)(V.z >> 16));    \
        A[6] += bf2f((u16)(V.w & 0xffff)); A[7] += bf2f((u16)(V.w >> 16));    \
    }

// gather-mean over bf16 features: 16 lanes per dst row, 16B (8 cols) per lane.
// off1 holds inclusive ends; off1[row-1] (sentinel-safe) is the start.
__global__ __launch_bounds__(256) void gatherb_kernel(const u16* __restrict__ feat,
                                                      const int* __restrict__ off1,
                                                      const int* __restrict__ pool,
                                                      int n,
                                                      u16* __restrict__ agg) {
    int row = blockIdx.x * 16 + (threadIdx.x >> 4);
    if (row >= n) return;
    int lane = (threadIdx.x & 15) * 8;
    int start = off1[row - 1];
    int end = off1[row];
    float a0[8], a1[8], a2[8], a3[8];
#pragma unroll
    for (int k = 0; k < 8; ++k) { a0[k] = 0.f; a1[k] = 0.f; a2[k] = 0.f; a3[k] = 0.f; }
    int j = start;
    for (; j + 4 <= end; j += 4) {
        int s0 = pool[j], s1 = pool[j + 1], s2 = pool[j + 2], s3 = pool[j + 3];
        uint4 v0 = *(const uint4*)&feat[(i64)s0 * H_ + lane];
        uint4 v1 = *(const uint4*)&feat[(i64)s1 * H_ + lane];
        uint4 v2 = *(const uint4*)&feat[(i64)s2 * H_ + lane];
        uint4 v3 = *(const uint4*)&feat[(i64)s3 * H_ + lane];
        ACC8(a0, v0); ACC8(a1, v1); ACC8(a2, v2); ACC8(a3, v3);
    }
    for (; j < end; ++j) {
        int s0 = pool[j];
        uint4 v0 = *(const uint4*)&feat[(i64)s0 * H_ + lane];
        ACC8(a0, v0);
    }
    float inv = 1.0f / fmaxf((float)(end - start), 1.0f);
    uint4 o;
    float r0, r1;
    r0 = (a0[0] + a1[0] + a2[0] + a3[0]) * inv; r1 = (a0[1] + a1[1] + a2[1] + a3[1]) * inv;
    o.x = (u32)f2bf(r0) | ((u32)f2bf(r1) << 16);
    r0 = (a0[2] + a1[2] + a2[2] + a3[2]) * inv; r1 = (a0[3] + a1[3] + a2[3] + a3[3]) * inv;
    o.y = (u32)f2bf(r0) | ((u32)f2bf(r1) << 16);
    r0 = (a0[4] + a1[4] + a2[4] + a3[4]) * inv; r1 = (a0[5] + a1[5] + a2[5] + a3[5]) * inv;
    o.z = (u32)f2bf(r0) | ((u32)f2bf(r1) << 16);
    r0 = (a0[6] + a1[6] + a2[6] + a3[6]) * inv; r1 = (a0[7] + a1[7] + a2[7] + a3[7]) * inv;
    o.w = (u32)f2bf(r0) | ((u32)f2bf(r1) << 16);
    *(uint4*)&agg[(i64)row * H_ + lane] = o;
}

// ---- weight prep -> frag-tiled bf16.
// frag layout: index = ((kc*8 + nt)*64 + l)*8 + e  holds  W_T[n=nt*16+(l&15)][k=kc*32+((l>>4)<<3)+e]
// logK==8 (liW): truncation hi/lo split into WTH/WTL (3-term x GEMM).
// logK==7 (dual slots, sum of up to 3 sources): single RTN bf16 into WTH.
struct WJob {
    const float* s0; const float* s1; const float* s2;
    int logK; int base;
};
struct WJobs { WJob j[17]; };

__global__ __launch_bounds__(256) void wsplit_kernel(WJobs jobs, int njobs, int total,
                                                     u16* __restrict__ WTH,
                                                     u16* __restrict__ WTL) {
    int gid = blockIdx.x * 256 + threadIdx.x;
    if (gid >= total) return;
    int ji = 0;
    for (int i = 1; i < 17; ++i)
        if (i < njobs && gid >= jobs.j[i].base) ji = i;
    WJob jb = jobs.j[ji];
    int local = gid - jb.base;
    int e = local & 7;
    int l = (local >> 3) & 63;
    int nt = (local >> 9) & 7;
    int kc = local >> 12;
    int n = nt * 16 + (l & 15);
    int k = kc * 32 + ((l >> 4) << 3) + e;
    i64 si = (i64)k * 128 + n;
    float v = jb.s0[si];
    if (jb.s1 != nullptr) v += jb.s1[si] + jb.s2[si];
    if (jb.logK == 8) {
        u32 b = __float_as_uint(v);
        u16 h = (u16)(b >> 16);                   // truncation split: v = hi + lo
        float rem = v - __uint_as_float(b & 0xffff0000u);
        WTH[gid] = h;
        WTL[gid] = (u16)(__float_as_uint(rem) >> 16);
    } else {
        WTH[gid] = f2bf(v);                       // single RTN bf16
    }
}

// ---- x_item GEMM: fp32 A (xif, K=256), 3-term hi/lo split, bf16 output only ----
__device__ __forceinline__ void split8(const float* f, bf16x8& h, bf16x8& lo) {
#pragma unroll
    for (int i = 0; i < 8; ++i) {
        u32 b = __float_as_uint(f[i]);
        h[i] = (short)(u16)(b >> 16);
        float rem = f[i] - __uint_as_float(b & 0xffff0000u);
        lo[i] = (short)(u16)(__float_as_uint(rem) >> 16);
    }
}

__global__ __launch_bounds__(256) void mgemm_x_kernel(
    const float* __restrict__ A, const u16* __restrict__ Wh, const u16* __restrict__ Wl,
    const float* __restrict__ bias, u16* __restrict__ Cbf, int M) {
    int t = threadIdx.x;
    int w = t >> 6, l = t & 63;
    int lr = l & 15, lq = l >> 4;
    int m0 = blockIdx.x * 128 + w * 32;

    f32x4 acc[2][8];
#pragma unroll
    for (int mt = 0; mt < 2; ++mt)
#pragma unroll
        for (int nt = 0; nt < 8; ++nt) acc[mt][nt] = (f32x4){0.f, 0.f, 0.f, 0.f};

    for (int kc = 0; kc < 8; ++kc) {   // K = 256
        bf16x8 ah0, al0, ah1, al1;
        {
            int row = m0 + lr;
            float f[8];
            if (row < M) {
                const float* ap = &A[(i64)row * FEAT_ + kc * 32 + lq * 8];
                *(float4*)&f[0] = *(const float4*)ap;
                *(float4*)&f[4] = *(const float4*)(ap + 4);
            } else {
#pragma unroll
                for (int i = 0; i < 8; ++i) f[i] = 0.f;
            }
            split8(f, ah0, al0);
        }
        {
            int row = m0 + 16 + lr;
            float f[8];
            if (row < M) {
                const float* ap = &A[(i64)row * FEAT_ + kc * 32 + lq * 8];
                *(float4*)&f[0] = *(const float4*)ap;
                *(float4*)&f[4] = *(const float4*)(ap + 4);
            } else {
#pragma unroll
                for (int i = 0; i < 8; ++i) f[i] = 0.f;
            }
            split8(f, ah1, al1);
        }
        const u16* whp = Wh + ((i64)kc * 8) * 512 + (i64)l * 8;
        const u16* wlp = Wl + ((i64)kc * 8) * 512 + (i64)l * 8;
#pragma unroll
        for (int nt = 0; nt < 8; ++nt) {
            bf16x8 bh = *(const bf16x8*)(whp + nt * 512);
            bf16x8 bl = *(const bf16x8*)(wlp + nt * 512);
            acc[0][nt] = __builtin_amdgcn_mfma_f32_16x16x32_bf16(ah0, bh, acc[0][nt], 0, 0, 0);
            acc[1][nt] = __builtin_amdgcn_mfma_f32_16x16x32_bf16(ah1, bh, acc[1][nt], 0, 0, 0);
            acc[0][nt] = __builtin_amdgcn_mfma_f32_16x16x32_bf16(al0, bh, acc[0][nt], 0, 0, 0);
            acc[1][nt] = __builtin_amdgcn_mfma_f32_16x16x32_bf16(al1, bh, acc[1][nt], 0, 0, 0);
            acc[0][nt] = __builtin_amdgcn_mfma_f32_16x16x32_bf16(ah0, bl, acc[0][nt], 0, 0, 0);
            acc[1][nt] = __builtin_amdgcn_mfma_f32_16x16x32_bf16(ah1, bl, acc[1][nt], 0, 0, 0);
        }
    }
#pragma unroll
    for (int nt = 0; nt < 8; ++nt) {
        int col = nt * 16 + lr;
        float bb = bias[col];
#pragma unroll
        for (int mt = 0; mt < 2; ++mt) {
#pragma unroll
            for (int r = 0; r < 4; ++r) {
                int row = m0 + mt * 16 + (lq << 2) + r;
                if (row < M) Cbf[(i64)row * H_ + col] = f2bf(acc[mt][nt][r] + bb);
            }
        }
    }
}

// ---- dual GEMM, bf16 A operands (K=128 each), single RTN bf16 W ----
// out = relu(0.5*(A1@W1 + A2@W2) + 0.5*(b1+b2)); writes fp32 C and/or bf16 Cbf.
// If fout != null (final IA GEMM): also fused = w0*fu + w1*fi + w2*out with
// w = softmax(alpha); block 0 thread 0 writes wout[0..2].
__global__ __launch_bounds__(256) void mgemm_d_kernel(
    const u16* __restrict__ A1, const u16* __restrict__ W1,
    const u16* __restrict__ A2, const u16* __restrict__ W2,
    const float* __restrict__ b1, const float* __restrict__ b2,
    float* __restrict__ C, u16* __restrict__ Cbf, int M,
    const float* __restrict__ alpha, const float* __restrict__ fu,
    const float* __restrict__ fi, float* __restrict__ fout,
    float* __restrict__ wout) {
    int t = threadIdx.x;
    int w = t >> 6, l = t & 63;
    int lr = l & 15, lq = l >> 4;
    int m0 = blockIdx.x * 128 + w * 32;

    f32x4 acc[2][8];
#pragma unroll
    for (int mt = 0; mt < 2; ++mt)
#pragma unroll
        for (int nt = 0; nt < 8; ++nt) acc[mt][nt] = (f32x4){0.f, 0.f, 0.f, 0.f};

#pragma unroll
    for (int mat = 0; mat < 2; ++mat) {
        const u16* A = mat ? A2 : A1;
        const u16* W = mat ? W2 : W1;
#pragma unroll
        for (int kc = 0; kc < 4; ++kc) {   // K = 128
            bf16x8 a0 = {0, 0, 0, 0, 0, 0, 0, 0}, a1 = {0, 0, 0, 0, 0, 0, 0, 0};
            int row0 = m0 + lr, row1 = m0 + 16 + lr;
            if (row0 < M) a0 = *(const bf16x8*)&A[(i64)row0 * H_ + kc * 32 + lq * 8];
            if (row1 < M) a1 = *(const bf16x8*)&A[(i64)row1 * H_ + kc * 32 + lq * 8];
            const u16* wp = W + ((i64)kc * 8) * 512 + (i64)l * 8;
#pragma unroll
            for (int nt = 0; nt < 8; ++nt) {
                bf16x8 bw = *(const bf16x8*)(wp + nt * 512);
                acc[0][nt] = __builtin_amdgcn_mfma_f32_16x16x32_bf16(a0, bw, acc[0][nt], 0, 0, 0);
                acc[1][nt] = __builtin_amdgcn_mfma_f32_16x16x32_bf16(a1, bw, acc[1][nt], 0, 0, 0);
            }
        }
    }

    float w0 = 0.f, w1 = 0.f, w2 = 0.f;
    if (fout != nullptr) {
        float x0 = alpha[0], x1 = alpha[1], x2 = alpha[2];
        float mx = fmaxf(x0, fmaxf(x1, x2));
        float e0 = __expf(x0 - mx), e1 = __expf(x1 - mx), e2 = __expf(x2 - mx);
        float inv = 1.f / (e0 + e1 + e2);
        w0 = e0 * inv; w1 = e1 * inv; w2 = e2 * inv;
        if (blockIdx.x == 0 && t == 0) { wout[0] = w0; wout[1] = w1; wout[2] = w2; }
    }

#pragma unroll
    for (int nt = 0; nt < 8; ++nt) {
        int col = nt * 16 + lr;
        float bb = 0.5f * (b1[col] + b2[col]);
#pragma unroll
        for (int mt = 0; mt < 2; ++mt) {
#pragma unroll
            for (int r = 0; r < 4; ++r) {
                int row = m0 + mt * 16 + (lq << 2) + r;
                if (row < M) {
                    i64 idx = (i64)row * H_ + col;
                    float o = fmaxf(0.5f * acc[mt][nt][r] + bb, 0.f);
                    if (C != nullptr) C[idx] = o;
                    if (Cbf != nullptr) Cbf[idx] = f2bf(o);
                    if (fout != nullptr) fout[idx] = w0 * fu[idx] + w1 * fi[idx] + w2 * o;
                }
            }
        }
    }
}

extern "C" void kernel_launch(void* const* d_in, const int* in_sizes, int n_in,
                              void* d_out, int out_size, void* d_ws, size_t ws_size,
                              hipStream_t stream) {
    const float* xif  = (const float*)d_in[0];
    const float* uemb = (const float*)d_in[1];
    const float* aemb = (const float*)d_in[2];
    const float* liW  = (const float*)d_in[3];
    const float* lib  = (const float*)d_in[4];
    const float* uiWl = (const float*)d_in[5];
    const float* uibl = (const float*)d_in[6];
    const float* uiWr = (const float*)d_in[7];
    const float* iiWl = (const float*)d_in[8];
    const float* iibl = (const float*)d_in[9];
    const float* iiWr = (const float*)d_in[10];
    const float* iaWl = (const float*)d_in[11];
    const float* iabl = (const float*)d_in[12];
    const float* iaWr = (const float*)d_in[13];
    const float* alpha = (const float*)d_in[14];
    const int* er = (const int*)d_in[15];
    const int* es = (const int*)d_in[16];
    const int* eh = (const int*)d_in[17];

    float* out = (float*)d_out;
    float* FUSED  = out;
    float* OUT_UI = out + (i64)NI_ * H_;
    float* OUT_II = out + (i64)2 * NI_ * H_;
    float* OUT_IA = out + (i64)3 * NI_ * H_;
    float* WOUT   = out + (i64)4 * NI_ * H_;

    // ---- workspace layout: bf16 region first (16B-aligned), then ints ----
    u16* u = (u16*)d_ws;
    i64 uo = 0;
    u16* WTH    = u + uo; uo += 294912;
    u16* WTL    = u + uo; uo += 294912;
    u16* X_bf   = u + uo; uo += (i64)NI_ * H_;
    u16* HI1_bf = u + uo; uo += (i64)NI_ * H_;
    u16* HU1_bf = u + uo; uo += (i64)NU_ * H_;
    u16* HA1_bf = u + uo; uo += (i64)NA_ * H_;
    u16* AGG_bf = u + uo; uo += (i64)NU_ * H_;
    u16* UE_bf  = u + uo; uo += (i64)NU_ * H_;
    u16* AE_bf  = u + uo; uo += (i64)NA_ * H_;

    int* ip = (int*)(u + uo);
    i64 io = 0;
    int* OFF   = ip + io; io += NTOT_ + 4;        // [0]=sentinel; off1 = OFF+1
    int* SBB   = ip + io; io += 256;              // SB dense bases (from scan)
    int* SBC   = ip + io; io += 256;              // SB cursors (init sb<<16 -> ends)
    int* POOL  = ip + io; io += RTOT_;            // final CSR vals
    int* CPOOL = ip + io; io += (i64)NSB_ << 16;  // strided SB regions (16.4M ints)
    int* off1 = OFF + 1;

    // ---- CSR build: init -> LDS-binned scatter -> count scan -> per-SB place ----
    {
        sbinit_kernel<<<1, 256, 0, stream>>>(SBC, OFF);
        int nblk = (RTOT_ + 4095) / 4096;   // 733
        binA_kernel<<<nblk, 256, 0, stream>>>(er, es, eh, SBC, CPOOL);
        sbscan_kernel<<<1, 256, 0, stream>>>(SBC, SBB);
        binB_kernel<<<NSB_, 1024, 0, stream>>>(CPOOL, SBB, SBC, off1, POOL);
    }

    // ---- weight prep ----
    const float* famWl[8] = {uiWl, uiWl, uiWl, iiWl, iiWl, iaWl, iaWl, iaWl};
    const float* famWr[8] = {uiWr, uiWr, uiWr, iiWr, iiWr, iaWr, iaWr, iaWr};
    const float* famBl[8] = {uibl, uibl, uibl, iibl, iibl, iabl, iabl, iabl};
    const int eidx[8] = {0, 1, 4, 0, 2, 0, 1, 5};
    const int sidx[8] = {3, 2, 7, 1, 3, 3, 2, 6};

    WJobs jobs;
    jobs.j[0] = {liW, nullptr, nullptr, 8, 0};
    int base = 32768;
    for (int s = 0; s < 8; ++s) {
        jobs.j[1 + 2 * s] = {famWl[s] + (i64)eidx[s] * 16384, nullptr, nullptr, 7, base};
        base += 16384;
        jobs.j[2 + 2 * s] = {famWr[s] + (i64)eidx[s] * 16384,
                             famWl[s] + (i64)sidx[s] * 16384,
                             famWr[s] + (i64)sidx[s] * 16384, 7, base};
        base += 16384;
    }
    wsplit_kernel<<<(base + 255) / 256, 256, 0, stream>>>(jobs, 17, base, WTH, WTL);

    // ---- bf16 copies of input embedding tables ----
    tobf_kernel<<<((NU_ * H_ / 4) + 255) / 256, 256, 0, stream>>>(
        (const float4*)uemb, (ushort4*)UE_bf, (long)NU_ * H_ / 4);
    tobf_kernel<<<((NA_ * H_ / 4) + 255) / 256, 256, 0, stream>>>(
        (const float4*)aemb, (ushort4*)AE_bf, (long)NA_ * H_ / 4);

    // x_item = xif @ liW + lib  -> bf16 table
    mgemm_x_kernel<<<(NI_ + 127) / 128, 256, 0, stream>>>(xif, WTH, WTL, lib, X_bf, NI_);

    auto gath = [&](const u16* feat, int cbase, int ndst) {
        gatherb_kernel<<<(ndst + 15) / 16, 256, 0, stream>>>(feat, off1 + cbase, POOL, ndst, AGG_bf);
    };
    auto gemm2 = [&](int slot, const u16* A2m, float* Cout, u16* Cbfout, int M,
                     const float* al = nullptr, const float* fu = nullptr,
                     const float* fi = nullptr, float* fo = nullptr,
                     float* wo = nullptr) {
        const u16* w1 = WTH + 32768 + (i64)(2 * slot) * 16384;
        const u16* w2 = WTH + 32768 + (i64)(2 * slot + 1) * 16384;
        const float* be = famBl[slot] + (i64)eidx[slot] * 128;
        const float* bs = famBl[slot] + (i64)sidx[slot] * 128;
        mgemm_d_kernel<<<(M + 127) / 128, 256, 0, stream>>>(
            AGG_bf, w1, A2m, w2, be, bs, Cout, Cbfout, M, al, fu, fi, fo, wo);
    };

    // ---- UI branch ----
    gath(UE_bf, B_RI, NI_);
    gemm2(0, X_bf, nullptr, HI1_bf, NI_);
    gath(X_bf, B_RU, NU_);
    gemm2(1, UE_bf, nullptr, HU1_bf, NU_);
    gath(HU1_bf, B_RI, NI_);                 // L1 o_i only (o_u dead)
    gemm2(2, HI1_bf, OUT_UI, nullptr, NI_);

    // ---- II branch ----
    gath(X_bf, B_SI, NI_);
    gemm2(3, X_bf, nullptr, HI1_bf, NI_);
    gath(HI1_bf, B_SI, NI_);
    gemm2(4, HI1_bf, OUT_II, nullptr, NI_);

    // ---- IA branch ----
    gath(X_bf, B_HA, NA_);
    gemm2(5, AE_bf, nullptr, HA1_bf, NA_);
    gath(AE_bf, B_HI, NI_);
    gemm2(6, X_bf, nullptr, HI1_bf, NI_);
    gath(HA1_bf, B_HI, NI_);                 // L1 o_i only (o_a dead)
    // final GEMM: writes OUT_IA, FUSED (reads completed OUT_UI/OUT_II), WOUT
    gemm2(7, HI1_bf, OUT_IA, nullptr, NI_, alpha, OUT_UI, OUT_II, FUSED, WOUT);
}